// Round 1
// baseline (3154.906 us; speedup 1.0000x reference)
//
#include <hip/hip_runtime.h>
#include <math.h>

static constexpr int NODES = 512;   // M
static constexpr int DC    = 256;   // coarse feature dim
static constexpr int MCT   = 512;   // coarse token count
static constexpr int DLOC  = 128;   // local feature dim
static constexpr int CC    = 256;   // correspondence count
static constexpr int KP    = 64;    // patch size
static constexpr int ZDIM  = 513;   // M+1

// ======================= NN + patches =======================
__global__ __launch_bounds__(256) void nn_kernel(const float* __restrict__ pts, int n,
                                                 const float* __restrict__ nodes,
                                                 int* __restrict__ out)
{
#pragma clang fp contract(off)
  __shared__ float nx[NODES], ny[NODES], nz[NODES], nn[NODES];
  for (int m = threadIdx.x; m < NODES; m += 256){
    float a = nodes[m*3+0], b = nodes[m*3+1], c = nodes[m*3+2];
    nx[m]=a; ny[m]=b; nz[m]=c;
    nn[m] = a*a + b*b + c*c;
  }
  __syncthreads();
  int i = blockIdx.x*256 + threadIdx.x;
  if (i >= n) return;
  float p0 = pts[i*3+0], p1 = pts[i*3+1], p2 = pts[i*3+2];
  float pp = p0*p0 + p1*p1 + p2*p2;
  float best = INFINITY; int bi = 0;
  for (int m = 0; m < NODES; ++m){
    float dot = fmaf(p2, nz[m], fmaf(p1, ny[m], p0*nx[m]));
    float d = (pp - 2.0f*dot) + nn[m];
    if (d < best){ best = d; bi = m; }
  }
  out[i] = bi;
}

__global__ __launch_bounds__(256) void hist_kernel(const int* __restrict__ id, int n,
                                                   int* __restrict__ hist)
{
  __shared__ int h[NODES];
  int t = threadIdx.x;
  h[t] = 0; h[t+256] = 0;
  __syncthreads();
  int i = blockIdx.x*256 + t;
  if (i < n) atomicAdd(&h[id[i]], 1);
  __syncthreads();
  hist[(long)blockIdx.x*NODES + t]       = h[t];
  hist[(long)blockIdx.x*NODES + t + 256] = h[t+256];
}

__global__ __launch_bounds__(512) void scan_kernel(int* __restrict__ hist, int nb,
                                                   int* __restrict__ counts)
{
  int m = threadIdx.x; // 512 threads, one per node
  int run = 0;
  for (int b = 0; b < nb; ++b){
    int t = hist[(long)b*NODES + m];
    hist[(long)b*NODES + m] = run;
    run += t;
  }
  counts[m] = run;
}

__global__ __launch_bounds__(256) void rank_kernel(const int* __restrict__ id, int n,
                                                   const int* __restrict__ hist,
                                                   int* __restrict__ patch)
{
  __shared__ int lid[256];
  int t = threadIdx.x;
  int i = blockIdx.x*256 + t;
  lid[t] = (i < n) ? id[i] : -1;
  __syncthreads();
  if (i >= n) return;
  int m = lid[t];
  int r = hist[(long)blockIdx.x*NODES + m];
  for (int q = 0; q < t; ++q) r += (lid[q] == m) ? 1 : 0;
  if (r < KP) patch[m*KP + r] = i;
}

// ======================= generic fp32 GEMM =======================
// Y[b][o][n] = sum_i W[o][i] * X(b,i,n) + bias[o] (+res) (relu?)
// X(b,i,n) = X1[b][i][n] for i<I1 else X2[b][i-I1][n]
__global__ __launch_bounds__(256) void gemm_f32(
    const float* __restrict__ W, const float* X1, const float* X2,
    const float* __restrict__ bias, const float* res, float* Y,
    int O, int I, int I1, int N,
    long sX1, long sX2, long sY, int relu)
{
  int b = blockIdx.z;
  const float* x1 = X1 + (long)b * sX1;
  const float* x2 = X2 ? (X2 + (long)b * sX2) : nullptr;
  float* y = Y + (long)b * sY;
  const float* r = res ? (res + (long)b * sY) : nullptr;

  int n0 = blockIdx.x * 64;
  int o0 = blockIdx.y * 64;
  int tid = threadIdx.x;
  int tx = tid & 15, ty = tid >> 4;

  __shared__ float Ws[16][68];
  __shared__ float Xs[16][68];

  float acc[4][4] = {};
  for (int k0 = 0; k0 < I; k0 += 16){
    {
      int e = tid * 4;
      int orow = e >> 4;        // 0..63
      int kcol = e & 15;        // 0,4,8,12
      float4 w4 = *reinterpret_cast<const float4*>(&W[(long)(o0 + orow) * I + k0 + kcol]);
      Ws[kcol+0][orow] = w4.x; Ws[kcol+1][orow] = w4.y;
      Ws[kcol+2][orow] = w4.z; Ws[kcol+3][orow] = w4.w;
    }
    {
      int e = tid * 4;
      int krow = e >> 6;        // 0..15
      int ncol = e & 63;        // mult of 4
      int i = k0 + krow;
      const float* src = (i < I1) ? &x1[(long)i * N + n0 + ncol]
                                  : &x2[(long)(i - I1) * N + n0 + ncol];
      *reinterpret_cast<float4*>(&Xs[krow][ncol]) = *reinterpret_cast<const float4*>(src);
    }
    __syncthreads();
#pragma unroll
    for (int kk = 0; kk < 16; ++kk){
      float a[4], bb[4];
#pragma unroll
      for (int i2 = 0; i2 < 4; ++i2) a[i2] = Ws[kk][ty*4+i2];
#pragma unroll
      for (int j = 0; j < 4; ++j) bb[j] = Xs[kk][tx*4+j];
#pragma unroll
      for (int i2 = 0; i2 < 4; ++i2)
#pragma unroll
        for (int j = 0; j < 4; ++j)
          acc[i2][j] += a[i2]*bb[j];
    }
    __syncthreads();
  }
#pragma unroll
  for (int i2 = 0; i2 < 4; ++i2){
    int o = o0 + ty*4 + i2;
    float bv = bias[o];
#pragma unroll
    for (int j = 0; j < 4; ++j){
      int n = n0 + tx*4 + j;
      float v = acc[i2][j] + bv;
      if (r) v += r[(long)o * N + n];
      if (relu) v = fmaxf(v, 0.f);
      y[(long)o * N + n] = v;
    }
  }
}

// C[b][n][m] = scale * sum_d A[b][d][n] * B[b][d][m]
__global__ __launch_bounds__(256) void gemm_tn(
    const float* __restrict__ A, const float* __restrict__ B, float* __restrict__ C,
    int Kd, int N, int Mc, int ldc, long sA, long sB, long sC, float scale)
{
  int b = blockIdx.z;
  const float* a = A + (long)b * sA;
  const float* bp = B + (long)b * sB;
  float* c = C + (long)b * sC;
  int m0 = blockIdx.x * 64, n0 = blockIdx.y * 64;
  int tid = threadIdx.x, tx = tid & 15, ty = tid >> 4;
  __shared__ float As[16][68], Bs[16][68];
  float acc[4][4] = {};
  for (int k0 = 0; k0 < Kd; k0 += 16){
    int e = tid * 4;
    int kr = e >> 6, nc = e & 63;
    *reinterpret_cast<float4*>(&As[kr][nc]) = *reinterpret_cast<const float4*>(&a[(long)(k0+kr)*N + n0 + nc]);
    *reinterpret_cast<float4*>(&Bs[kr][nc]) = *reinterpret_cast<const float4*>(&bp[(long)(k0+kr)*Mc + m0 + nc]);
    __syncthreads();
#pragma unroll
    for (int kk = 0; kk < 16; ++kk){
      float av[4], bv[4];
#pragma unroll
      for (int i = 0; i < 4; ++i) av[i] = As[kk][ty*4+i];
#pragma unroll
      for (int j = 0; j < 4; ++j) bv[j] = Bs[kk][tx*4+j];
#pragma unroll
      for (int i = 0; i < 4; ++i)
#pragma unroll
        for (int j = 0; j < 4; ++j) acc[i][j] += av[i]*bv[j];
    }
    __syncthreads();
  }
#pragma unroll
  for (int i = 0; i < 4; ++i)
#pragma unroll
    for (int j = 0; j < 4; ++j)
      c[(long)(n0 + ty*4 + i)*ldc + m0 + tx*4 + j] = acc[i][j] * scale;
}

// C[b][o][n] = sum_m P[b][o][m] * Q[b][n][m]
__global__ __launch_bounds__(256) void gemm_nt(
    const float* __restrict__ P, const float* __restrict__ Q, float* __restrict__ C,
    int O, int Nn, int Kd, long sP, long sQ, long sC)
{
  int b = blockIdx.z;
  const float* p = P + (long)b * sP;
  const float* q = Q + (long)b * sQ;
  float* c = C + (long)b * sC;
  int n0 = blockIdx.x * 64, o0 = blockIdx.y * 64;
  int tid = threadIdx.x, tx = tid & 15, ty = tid >> 4;
  __shared__ float Ps[64][20], Qs[64][20];
  float acc[4][4] = {};
  for (int k0 = 0; k0 < Kd; k0 += 16){
    int e = tid * 4;
    int row = e >> 4, col = e & 15;
    *reinterpret_cast<float4*>(&Ps[row][col]) = *reinterpret_cast<const float4*>(&p[(long)(o0+row)*Kd + k0 + col]);
    *reinterpret_cast<float4*>(&Qs[row][col]) = *reinterpret_cast<const float4*>(&q[(long)(n0+row)*Kd + k0 + col]);
    __syncthreads();
#pragma unroll
    for (int kk = 0; kk < 16; ++kk){
      float av[4], bv[4];
#pragma unroll
      for (int i = 0; i < 4; ++i) av[i] = Ps[ty*4+i][kk];
#pragma unroll
      for (int j = 0; j < 4; ++j) bv[j] = Qs[tx*4+j][kk];
#pragma unroll
      for (int i = 0; i < 4; ++i)
#pragma unroll
        for (int j = 0; j < 4; ++j) acc[i][j] += av[i]*bv[j];
    }
    __syncthreads();
  }
#pragma unroll
  for (int i = 0; i < 4; ++i)
#pragma unroll
    for (int j = 0; j < 4; ++j)
      c[(long)(o0 + ty*4 + i)*Nn + n0 + tx*4 + j] = acc[i][j];
}

// wave-per-row softmax, in place
__global__ __launch_bounds__(256) void softmax_rows(float* s, int nrows, int ncols)
{
  int row = blockIdx.x*4 + (threadIdx.x >> 6);
  if (row >= nrows) return;
  int lane = threadIdx.x & 63;
  float* p = s + (long)row * ncols;
  float mx = -INFINITY;
  for (int j = lane; j < ncols; j += 64) mx = fmaxf(mx, p[j]);
  for (int o = 32; o; o >>= 1) mx = fmaxf(mx, __shfl_xor(mx, o));
  float sum = 0.f;
  for (int j = lane; j < ncols; j += 64){ float e = expf(p[j]-mx); p[j]=e; sum+=e; }
  for (int o = 32; o; o >>= 1) sum += __shfl_xor(sum, o);
  for (int j = lane; j < ncols; j += 64) p[j] /= sum;
}

// ======================= fused local attention =======================
// per (c,h): msg[c][h*32+d][n] = sum_m softmax_m(q^T k /sqrt(32))[n][m] * v[c][h*32+d][m]
__global__ __launch_bounds__(256) void local_attn(const float* __restrict__ q,
                                                  const float* __restrict__ k,
                                                  const float* __restrict__ v,
                                                  float* __restrict__ msg)
{
  int c = blockIdx.x >> 2, h = blockIdx.x & 3;
  long base = ((long)c*DLOC + h*32) * 64;
  __shared__ float qs[32][64], ks[32][64], vs[32][64];
  __shared__ float ss[64][65];
  int tid = threadIdx.x;
  for (int e = tid; e < 2048; e += 256){
    int d = e >> 6, n = e & 63;
    qs[d][n] = q[base + e];
    ks[d][n] = k[base + e];
    vs[d][n] = v[base + e];
  }
  __syncthreads();
  const float SC = (float)(1.0/5.656854249492381); // 1/sqrt(32)
  for (int e = tid; e < 4096; e += 256){
    int n = e >> 6, m = e & 63;
    float s = 0.f;
#pragma unroll 8
    for (int d = 0; d < 32; ++d) s = fmaf(qs[d][n], ks[d][m], s);
    ss[n][m] = s * SC;
  }
  __syncthreads();
  // softmax rows: 4 lanes per row
  {
    int row = tid >> 2, sub = tid & 3;
    float mx = -INFINITY;
    for (int j = sub; j < 64; j += 4) mx = fmaxf(mx, ss[row][j]);
    mx = fmaxf(mx, __shfl_xor(mx, 1)); mx = fmaxf(mx, __shfl_xor(mx, 2));
    float sum = 0.f;
    for (int j = sub; j < 64; j += 4){ float e = expf(ss[row][j]-mx); ss[row][j]=e; sum+=e; }
    sum += __shfl_xor(sum, 1); sum += __shfl_xor(sum, 2);
    for (int j = sub; j < 64; j += 4) ss[row][j] /= sum;
  }
  __syncthreads();
  for (int e = tid; e < 2048; e += 256){
    int d = e >> 6, n = e & 63;
    float s = 0.f;
#pragma unroll 8
    for (int m = 0; m < 64; ++m) s = fmaf(ss[n][m], vs[d][m], s);
    msg[base + e] = s;
  }
}

// ======================= transport =======================
__global__ __launch_bounds__(256) void fill_border(float* Z, const float* __restrict__ alpha)
{
  int i = blockIdx.x*256 + threadIdx.x;
  if (i < ZDIM){
    float a = alpha[0];
    Z[(long)i*ZDIM + (ZDIM-1)] = a;
    Z[(long)(ZDIM-1)*ZDIM + i] = a;
  }
}

__global__ __launch_bounds__(256) void transpose_k(const float* __restrict__ A,
                                                   float* __restrict__ B, int n)
{
  __shared__ float t[32][33];
  int bx = blockIdx.x*32, by = blockIdx.y*32;
  int lx = threadIdx.x & 31, ly0 = threadIdx.x >> 5; // 32x8
  for (int dy = 0; dy < 32; dy += 8){
    int x = bx + lx, y = by + ly0 + dy;
    if (x < n && y < n) t[ly0+dy][lx] = A[(long)y*n + x];
  }
  __syncthreads();
  for (int dy = 0; dy < 32; dy += 8){
    int x = by + lx, y = bx + ly0 + dy;
    if (x < n && y < n) B[(long)y*n + x] = t[lx][ly0+dy];
  }
}

// wout[r] = (r<512? base: last) - logsumexp_j(Zr[r][j] + win[j])
__global__ __launch_bounds__(256) void lse_phase(const float* __restrict__ Zr,
                                                 const float* __restrict__ win,
                                                 float* __restrict__ wout,
                                                 float base, float last)
{
  __shared__ float red[256];
  int r = blockIdx.x;
  const float* z = Zr + (long)r * ZDIM;
  int tid = threadIdx.x;
  float mx = -INFINITY;
  for (int j = tid; j < ZDIM; j += 256) mx = fmaxf(mx, z[j] + win[j]);
  red[tid] = mx; __syncthreads();
  for (int s = 128; s > 0; s >>= 1){ if (tid < s) red[tid] = fmaxf(red[tid], red[tid+s]); __syncthreads(); }
  mx = red[0]; __syncthreads();
  float sum = 0.f;
  for (int j = tid; j < ZDIM; j += 256) sum += expf(z[j] + win[j] - mx);
  red[tid] = sum; __syncthreads();
  for (int s = 128; s > 0; s >>= 1){ if (tid < s) red[tid] += red[tid+s]; __syncthreads(); }
  if (tid == 0) wout[r] = ((r < ZDIM-1) ? base : last) - (mx + logf(red[0]));
}

__global__ __launch_bounds__(256) void transport_out(const float* __restrict__ Z,
                                                     const float* __restrict__ u,
                                                     const float* __restrict__ v,
                                                     float norm, float* __restrict__ out)
{
  int idx = blockIdx.x*256 + threadIdx.x;
  if (idx >= ZDIM*ZDIM) return;
  int r = idx / ZDIM, c = idx % ZDIM;
  out[idx] = Z[idx] + u[r] + v[c] - norm;
}

// ======================= local gather =======================
__global__ __launch_bounds__(256) void gather_feats(const float* __restrict__ F,
                                                    const int* __restrict__ patch,
                                                    const int* __restrict__ corr,
                                                    int side, float* __restrict__ out)
{
  int c = blockIdx.x;
  __shared__ int sel[KP];
  __shared__ float t[DLOC][65];
  int tid = threadIdx.x;
  if (tid < KP){
    int node = corr[c*2 + side];
    sel[tid] = patch[node*KP + tid];
  }
  __syncthreads();
  for (int e = tid; e < KP*DLOC; e += 256){
    int n = e >> 7, d = e & 127;
    t[d][n] = F[(long)sel[n]*DLOC + d];
  }
  __syncthreads();
  for (int e = tid; e < DLOC*KP; e += 256){
    int d = e >> 6, n = e & 63;
    out[((long)c*DLOC + d)*KP + n] = t[d][n];
  }
}

// ======================= local sinkhorn =======================
__global__ __launch_bounds__(256) void sinkhorn_local(const float* __restrict__ lsraw,
                                                      const int* __restrict__ corr,
                                                      const int* __restrict__ cnt_s,
                                                      const int* __restrict__ cnt_t,
                                                      float* __restrict__ out)
{
  int c = blockIdx.x;
  int sn = corr[c*2], tn = corr[c*2+1];
  int cs = cnt_s[sn], ct = cnt_t[tn];
  __shared__ float la[65][66];
  int tid = threadIdx.x;
  for (int e = tid; e < 65*65; e += 256){
    int r = e / 65, col = e % 65;
    float v = 0.f;
    if (r < 64 && col < 64){
      v = lsraw[((long)c*64 + r)*64 + col];
      if (r >= cs || col >= ct) v = -1000000.0f;
    }
    la[r][col] = v;
  }
  __syncthreads();
  int row = tid >> 2, sub = tid & 3;
  for (int it = 0; it < 50; ++it){
    // rows 0..63 normalized over all 65 cols
    {
      float mx = -INFINITY;
      for (int j = sub; j < 65; j += 4) mx = fmaxf(mx, la[row][j]);
      mx = fmaxf(mx, __shfl_xor(mx, 1)); mx = fmaxf(mx, __shfl_xor(mx, 2));
      float s = 0.f;
      for (int j = sub; j < 65; j += 4) s += expf(la[row][j]-mx);
      s += __shfl_xor(s, 1); s += __shfl_xor(s, 2);
      float lse = mx + logf(s);
      for (int j = sub; j < 65; j += 4) la[row][j] -= lse;
    }
    __syncthreads();
    // cols 0..63 normalized over all 65 rows
    {
      float mx = -INFINITY;
      for (int rr = sub; rr < 65; rr += 4) mx = fmaxf(mx, la[rr][row]);
      mx = fmaxf(mx, __shfl_xor(mx, 1)); mx = fmaxf(mx, __shfl_xor(mx, 2));
      float s = 0.f;
      for (int rr = sub; rr < 65; rr += 4) s += expf(la[rr][row]-mx);
      s += __shfl_xor(s, 1); s += __shfl_xor(s, 2);
      float lse = mx + logf(s);
      for (int rr = sub; rr < 65; rr += 4) la[rr][row] -= lse;
    }
    __syncthreads();
  }
  for (int e = tid; e < 65*65; e += 256)
    out[(long)c*4225 + e] = la[e/65][e%65];
}

// ======================= GT =======================
__global__ __launch_bounds__(256) void gt_kernel(const float* __restrict__ sraw,
                                                 const float* __restrict__ traw,
                                                 const float* __restrict__ rot,
                                                 const float* __restrict__ trans,
                                                 const int* __restrict__ patch_s,
                                                 const int* __restrict__ patch_t,
                                                 const int* __restrict__ corr,
                                                 const int* __restrict__ cnt_s,
                                                 const int* __restrict__ cnt_t,
                                                 float* __restrict__ out)
{
#pragma clang fp contract(off)
  int c = blockIdx.x, tid = threadIdx.x;
  int sn = corr[c*2], tn = corr[c*2+1];
  int cs = cnt_s[sn], ct = cnt_t[tn];
  __shared__ float sx[64], sy[64], sz[64], spp[64];
  __shared__ float txa[64], tya[64], tza[64], tpp[64];
  __shared__ float g[64][65];
  __shared__ float rowsum[64], colsum[64];
  if (tid < 64){
    int idx = patch_s[sn*KP + tid];
    float p0 = sraw[(long)idx*3], p1 = sraw[(long)idx*3+1], p2 = sraw[(long)idx*3+2];
    float a0 = fmaf(rot[2], p2, fmaf(rot[1], p1, rot[0]*p0)) + trans[0];
    float a1 = fmaf(rot[5], p2, fmaf(rot[4], p1, rot[3]*p0)) + trans[1];
    float a2 = fmaf(rot[8], p2, fmaf(rot[7], p1, rot[6]*p0)) + trans[2];
    sx[tid]=a0; sy[tid]=a1; sz[tid]=a2;
    spp[tid] = a0*a0 + a1*a1 + a2*a2;
  } else if (tid < 128){
    int l = tid - 64;
    int idx = patch_t[tn*KP + l];
    float p0 = traw[(long)idx*3], p1 = traw[(long)idx*3+1], p2 = traw[(long)idx*3+2];
    txa[l]=p0; tya[l]=p1; tza[l]=p2;
    tpp[l] = p0*p0 + p1*p1 + p2*p2;
  }
  __syncthreads();
  for (int e = tid; e < 4096; e += 256){
    int n = e >> 6, m = e & 63;
    float dot = fmaf(sz[n], tza[m], fmaf(sy[n], tya[m], sx[n]*txa[m]));
    float d2 = (spp[n] + tpp[m]) - 2.0f*dot;
    d2 = fmaxf(d2, 0.f);
    g[n][m] = (sqrtf(d2) < 0.1f) ? 1.f : 0.f;
  }
  __syncthreads();
  if (tid < 64){
    float s = 0.f;
    for (int m = 0; m < 64; ++m) s += g[tid][m];
    rowsum[tid] = fmaxf(1.f - s, 0.f);
  } else if (tid < 128){
    int m = tid - 64;
    float s = 0.f;
    for (int n = 0; n < 64; ++n) s += g[n][m];
    colsum[m] = fmaxf(1.f - s, 0.f);
  }
  __syncthreads();
  float* o = out + (long)c*4225;
  for (int e = tid; e < 4225; e += 256){
    int r = e / 65, col = e % 65;
    float v;
    if (r < 64 && col < 64) v = g[r][col];
    else if (r < 64)        v = rowsum[r];
    else if (col < 64)      v = colsum[col];
    else                    v = 0.f;
    if (r < 64 && r >= cs)    v = 0.f;
    if (col < 64 && col >= ct) v = 0.f;
    o[e] = v;
  }
}

// ======================= host =======================
extern "C" void kernel_launch(void* const* d_in, const int* in_sizes, int n_in,
                              void* d_out, int out_size, void* d_ws, size_t ws_size,
                              hipStream_t stream)
{
  const float* src_pcd_c  = (const float*)d_in[0];
  const float* tgt_pcd_c  = (const float*)d_in[1];
  const float* src_node_c = (const float*)d_in[2];
  const float* tgt_node_c = (const float*)d_in[3];
  const float* src_feats  = (const float*)d_in[4];
  const float* tgt_feats  = (const float*)d_in[5];
  const float* src_final  = (const float*)d_in[6];
  const float* tgt_final  = (const float*)d_in[7];
  const float* rot        = (const float*)d_in[8];
  const float* trans      = (const float*)d_in[9];
  const float* src_raw    = (const float*)d_in[10];
  const float* tgt_raw    = (const float*)d_in[11];
  const int*   node_corr  = (const int*)d_in[12];
  const float* c_wq = (const float*)d_in[13]; const float* c_bq = (const float*)d_in[14];
  const float* c_wk = (const float*)d_in[15]; const float* c_bk = (const float*)d_in[16];
  const float* c_wv = (const float*)d_in[17]; const float* c_bv = (const float*)d_in[18];
  const float* c_wm = (const float*)d_in[19]; const float* c_bm = (const float*)d_in[20];
  const float* c_w1 = (const float*)d_in[21]; const float* c_b1 = (const float*)d_in[22];
  const float* c_w2 = (const float*)d_in[23]; const float* c_b2 = (const float*)d_in[24];
  const float* l_wq = (const float*)d_in[25]; const float* l_bq = (const float*)d_in[26];
  const float* l_wk = (const float*)d_in[27]; const float* l_bk = (const float*)d_in[28];
  const float* l_wv = (const float*)d_in[29]; const float* l_bv = (const float*)d_in[30];
  const float* l_wm = (const float*)d_in[31]; const float* l_bm = (const float*)d_in[32];
  const float* l_w1 = (const float*)d_in[33]; const float* l_b1 = (const float*)d_in[34];
  const float* l_w2 = (const float*)d_in[35]; const float* l_b2 = (const float*)d_in[36];
  const float* fp_w = (const float*)d_in[37]; const float* fp_b = (const float*)d_in[38];
  const float* lfp_w = (const float*)d_in[39]; const float* lfp_b = (const float*)d_in[40];
  const float* bin_score = (const float*)d_in[41];

  const int NS = in_sizes[0] / 3;
  const int NT = in_sizes[1] / 3;

  // ---- workspace layout ----
  float* FB = (float*)d_ws;
  size_t off = 0;
  auto falloc = [&](size_t n){ float* p = FB + off; off += (n + 63) & ~size_t(63); return p; };
  // local-phase (large) region
  float* spf  = falloc(2097152);
  float* tpf  = falloc(2097152);
  float* lq   = falloc(2097152);
  float* lk   = falloc(2097152);
  float* lv   = falloc(2097152);
  float* lmsg = falloc(2097152);
  float* lh1  = falloc(4194304);
  float* lsraw= falloc(1048576);
  // coarse phase overlays the start of the same region (runs before gathers)
  size_t coff = 0;
  auto calloc2 = [&](size_t n){ float* p = FB + coff; coff += (n + 63) & ~size_t(63); return p; };
  float* sf   = calloc2(DC*MCT);
  float* tf   = calloc2(DC*MCT);
  float* cq   = calloc2(DC*MCT);
  float* ck   = calloc2(DC*MCT);
  float* cv   = calloc2(DC*MCT);
  float* cs   = calloc2(4*MCT*MCT);
  float* cmsg = calloc2(DC*MCT);
  float* cmsg2= calloc2(DC*MCT);
  float* ch1  = calloc2(2*DC*MCT);
  float* sfp  = calloc2(DC*MCT);
  float* tfp  = calloc2(DC*MCT);
  float* Zx   = calloc2(ZDIM*ZDIM);
  float* Zt   = calloc2(ZDIM*ZDIM);
  float* uu   = calloc2(640);
  float* vv   = calloc2(640);
  // int region
  int* IB = (int*)(FB + off);
  size_t ioff = 0;
  auto ialloc = [&](size_t n){ int* p = IB + ioff; ioff += (n + 63) & ~size_t(63); return p; };
  int* id_s = ialloc(NS);
  int* id_t = ialloc(NT);
  const int nbs = (NS + 255) / 256, nbt = (NT + 255) / 256;
  int* hist_s = ialloc((size_t)nbs * NODES);
  int* hist_t = ialloc((size_t)nbt * NODES);
  int* cnt_s = ialloc(NODES);
  int* cnt_t = ialloc(NODES);
  int* patch_s = ialloc(NODES*KP);
  int* patch_t = ialloc(NODES*KP);

  float* out0 = (float*)d_out;
  float* out_ls = out0 + ZDIM*ZDIM;
  float* out_gt = out_ls + (long)CC*65*65;

  // ---- phase 1: NN + patches ----
  nn_kernel<<<nbs, 256, 0, stream>>>(src_pcd_c, NS, src_node_c, id_s);
  nn_kernel<<<nbt, 256, 0, stream>>>(tgt_pcd_c, NT, tgt_node_c, id_t);
  hist_kernel<<<nbs, 256, 0, stream>>>(id_s, NS, hist_s);
  hist_kernel<<<nbt, 256, 0, stream>>>(id_t, NT, hist_t);
  scan_kernel<<<1, 512, 0, stream>>>(hist_s, nbs, cnt_s);
  scan_kernel<<<1, 512, 0, stream>>>(hist_t, nbt, cnt_t);
  hipMemsetAsync(patch_s, 0, NODES*KP*sizeof(int), stream);
  hipMemsetAsync(patch_t, 0, NODES*KP*sizeof(int), stream);
  rank_kernel<<<nbs, 256, 0, stream>>>(id_s, NS, hist_s, patch_s);
  rank_kernel<<<nbt, 256, 0, stream>>>(id_t, NT, hist_t, patch_t);

  // ---- phase 2: coarse transformer + transport ----
  hipMemcpyAsync(sf, src_feats, DC*MCT*sizeof(float), hipMemcpyDeviceToDevice, stream);
  hipMemcpyAsync(tf, tgt_feats, DC*MCT*sizeof(float), hipMemcpyDeviceToDevice, stream);

  auto gemm = [&](const float* W, const float* X1, const float* X2, const float* bias,
                  const float* res, float* Y, int O, int I, int I1, int N,
                  long sX, long sY, int batch, int relu){
    dim3 g(N/64, O/64, batch);
    gemm_f32<<<g, 256, 0, stream>>>(W, X1, X2, bias, res, Y, O, I, I1, N, sX, sX, sY, relu);
  };

  auto coarse_block = [&](int l, float* x, float* srcb){
    const float* wq = c_wq + (size_t)l*DC*DC; const float* bq = c_bq + (size_t)l*DC;
    const float* wk = c_wk + (size_t)l*DC*DC; const float* bk = c_bk + (size_t)l*DC;
    const float* wv = c_wv + (size_t)l*DC*DC; const float* bv = c_bv + (size_t)l*DC;
    const float* wm = c_wm + (size_t)l*DC*DC; const float* bm = c_bm + (size_t)l*DC;
    const float* w1 = c_w1 + (size_t)l*4*DC*DC; const float* b1 = c_b1 + (size_t)l*2*DC;
    const float* w2 = c_w2 + (size_t)l*2*DC*DC; const float* b2 = c_b2 + (size_t)l*DC;
    gemm(wq, x,    nullptr, bq, nullptr, cq, DC, DC, DC, MCT, 0, 0, 1, 0);
    gemm(wk, srcb, nullptr, bk, nullptr, ck, DC, DC, DC, MCT, 0, 0, 1, 0);
    gemm(wv, srcb, nullptr, bv, nullptr, cv, DC, DC, DC, MCT, 0, 0, 1, 0);
    gemm_tn<<<dim3(8,8,4), 256, 0, stream>>>(cq, ck, cs, 64, MCT, MCT, MCT,
                                             (long)64*MCT, (long)64*MCT, (long)MCT*MCT, 0.125f);
    softmax_rows<<<(4*MCT)/4, 256, 0, stream>>>(cs, 4*MCT, MCT);
    gemm_nt<<<dim3(8,1,4), 256, 0, stream>>>(cv, cs, cmsg, 64, MCT, MCT,
                                             (long)64*MCT, (long)MCT*MCT, (long)64*MCT);
    gemm(wm, cmsg, nullptr, bm, nullptr, cmsg2, DC, DC, DC, MCT, 0, 0, 1, 0);
    gemm(w1, x, cmsg2, b1, nullptr, ch1, 2*DC, 2*DC, DC, MCT, 0, 0, 1, 1);
    gemm(w2, ch1, nullptr, b2, x, x, DC, 2*DC, 2*DC, MCT, 0, 0, 1, 0);
  };
  coarse_block(0, sf, sf);
  coarse_block(0, tf, tf);
  coarse_block(1, sf, tf);
  coarse_block(1, tf, sf);
  coarse_block(2, sf, sf);
  coarse_block(2, tf, tf);

  gemm(fp_w, sf, nullptr, fp_b, nullptr, sfp, DC, DC, DC, MCT, 0, 0, 1, 0);
  gemm(fp_w, tf, nullptr, fp_b, nullptr, tfp, DC, DC, DC, MCT, 0, 0, 1, 0);
  gemm_tn<<<dim3(8,8,1), 256, 0, stream>>>(sfp, tfp, Zx, DC, MCT, MCT, ZDIM,
                                           0L, 0L, 0L, 0.0625f);
  fill_border<<<3, 256, 0, stream>>>(Zx, bin_score);
  transpose_k<<<dim3(17,17), 256, 0, stream>>>(Zx, Zt, ZDIM);
  hipMemsetAsync(uu, 0, 640*sizeof(float), stream);
  hipMemsetAsync(vv, 0, 640*sizeof(float), stream);
  const float NORM = (float)(-log(1024.0));
  const float LAST = (float)(log(512.0) - log(1024.0));
  for (int it = 0; it < 50; ++it){
    lse_phase<<<ZDIM, 256, 0, stream>>>(Zx, vv, uu, NORM, LAST);
    lse_phase<<<ZDIM, 256, 0, stream>>>(Zt, uu, vv, NORM, LAST);
  }
  transport_out<<<(ZDIM*ZDIM + 255)/256, 256, 0, stream>>>(Zx, uu, vv, NORM, out0);

  // ---- phase 3: local transformer + sinkhorn ----
  gather_feats<<<CC, 256, 0, stream>>>(src_final, patch_s, node_corr, 0, spf);
  gather_feats<<<CC, 256, 0, stream>>>(tgt_final, patch_t, node_corr, 1, tpf);

  auto local_block = [&](int l, float* x, float* srcb){
    const float* wq = l_wq + (size_t)l*DLOC*DLOC; const float* bq = l_bq + (size_t)l*DLOC;
    const float* wk = l_wk + (size_t)l*DLOC*DLOC; const float* bk = l_bk + (size_t)l*DLOC;
    const float* wv = l_wv + (size_t)l*DLOC*DLOC; const float* bv = l_bv + (size_t)l*DLOC;
    const float* wm = l_wm + (size_t)l*DLOC*DLOC; const float* bm = l_bm + (size_t)l*DLOC;
    const float* w1 = l_w1 + (size_t)l*4*DLOC*DLOC; const float* b1 = l_b1 + (size_t)l*2*DLOC;
    const float* w2 = l_w2 + (size_t)l*2*DLOC*DLOC; const float* b2 = l_b2 + (size_t)l*DLOC;
    const long sF = (long)DLOC*KP;     // 8192
    const long sH = (long)2*DLOC*KP;   // 16384
    gemm(wq, x,    nullptr, bq, nullptr, lq, DLOC, DLOC, DLOC, KP, sF, sF, CC, 0);
    gemm(wk, srcb, nullptr, bk, nullptr, lk, DLOC, DLOC, DLOC, KP, sF, sF, CC, 0);
    gemm(wv, srcb, nullptr, bv, nullptr, lv, DLOC, DLOC, DLOC, KP, sF, sF, CC, 0);
    local_attn<<<CC*4, 256, 0, stream>>>(lq, lk, lv, lmsg);
    gemm(wm, lmsg, nullptr, bm, nullptr, lq, DLOC, DLOC, DLOC, KP, sF, sF, CC, 0); // msg2 -> lq
    gemm(w1, x, lq, b1, nullptr, lh1, 2*DLOC, 2*DLOC, DLOC, KP, sF, sH, CC, 1);
    gemm(w2, lh1, nullptr, b2, x, x, DLOC, 2*DLOC, 2*DLOC, KP, sH, sF, CC, 0);
  };
  local_block(0, spf, spf);
  local_block(0, tpf, tpf);
  local_block(1, spf, tpf);
  local_block(1, tpf, spf);
  local_block(2, spf, spf);
  local_block(2, tpf, tpf);

  const long sF = (long)DLOC*KP;
  gemm(lfp_w, spf, nullptr, lfp_b, nullptr, lq, DLOC, DLOC, DLOC, KP, sF, sF, CC, 0);
  gemm(lfp_w, tpf, nullptr, lfp_b, nullptr, lk, DLOC, DLOC, DLOC, KP, sF, sF, CC, 0);
  gemm_tn<<<dim3(1,1,CC), 256, 0, stream>>>(lq, lk, lsraw, DLOC, KP, KP, KP,
                                            sF, sF, (long)KP*KP,
                                            (float)(1.0/11.313708498984761)); // 1/sqrt(128)
  sinkhorn_local<<<CC, 256, 0, stream>>>(lsraw, node_corr, cnt_s, cnt_t, out_ls);

  // ---- phase 4: GT ----
  gt_kernel<<<CC, 256, 0, stream>>>(src_raw, tgt_raw, rot, trans,
                                    patch_s, patch_t, node_corr, cnt_s, cnt_t, out_gt);

  (void)n_in; (void)out_size; (void)ws_size; (void)tgt_feats;
}

// Round 2
// 2291.253 us; speedup vs baseline: 1.3769x; 1.3769x over previous
//
#include <hip/hip_runtime.h>
#include <math.h>

static constexpr int NODES = 512;   // M
static constexpr int DC    = 256;   // coarse feature dim
static constexpr int MCT   = 512;   // coarse token count
static constexpr int DLOC  = 128;   // local feature dim
static constexpr int CC    = 256;   // correspondence count
static constexpr int KP    = 64;    // patch size
static constexpr int ZDIM  = 513;   // M+1

typedef unsigned short u16;
typedef short bf16x8 __attribute__((ext_vector_type(8)));
typedef float f32x4 __attribute__((ext_vector_type(4)));

__device__ __forceinline__ u16 f2b(float f){
  unsigned u = __float_as_uint(f);
  unsigned r = (u + 0x7FFF + ((u >> 16) & 1)) >> 16;
  return (u16)r;
}
__device__ __forceinline__ float b2f(u16 h){ return __uint_as_float(((unsigned)h) << 16); }

// ======================= NN + patches (unchanged — decision-exact) =======================
__global__ __launch_bounds__(256) void nn_kernel(const float* __restrict__ pts, int n,
                                                 const float* __restrict__ nodes,
                                                 int* __restrict__ out)
{
#pragma clang fp contract(off)
  __shared__ float nx[NODES], ny[NODES], nz[NODES], nn[NODES];
  for (int m = threadIdx.x; m < NODES; m += 256){
    float a = nodes[m*3+0], b = nodes[m*3+1], c = nodes[m*3+2];
    nx[m]=a; ny[m]=b; nz[m]=c;
    nn[m] = a*a + b*b + c*c;
  }
  __syncthreads();
  int i = blockIdx.x*256 + threadIdx.x;
  if (i >= n) return;
  float p0 = pts[i*3+0], p1 = pts[i*3+1], p2 = pts[i*3+2];
  float pp = p0*p0 + p1*p1 + p2*p2;
  float best = INFINITY; int bi = 0;
  for (int m = 0; m < NODES; ++m){
    float dot = fmaf(p2, nz[m], fmaf(p1, ny[m], p0*nx[m]));
    float d = (pp - 2.0f*dot) + nn[m];
    if (d < best){ best = d; bi = m; }
  }
  out[i] = bi;
}

__global__ __launch_bounds__(256) void hist_kernel(const int* __restrict__ id, int n,
                                                   int* __restrict__ hist)
{
  __shared__ int h[NODES];
  int t = threadIdx.x;
  h[t] = 0; h[t+256] = 0;
  __syncthreads();
  int i = blockIdx.x*256 + t;
  if (i < n) atomicAdd(&h[id[i]], 1);
  __syncthreads();
  hist[(long)blockIdx.x*NODES + t]       = h[t];
  hist[(long)blockIdx.x*NODES + t + 256] = h[t+256];
}

__global__ __launch_bounds__(512) void scan_kernel(int* __restrict__ hist, int nb,
                                                   int* __restrict__ counts)
{
  int m = threadIdx.x;
  int run = 0;
  for (int b = 0; b < nb; ++b){
    int t = hist[(long)b*NODES + m];
    hist[(long)b*NODES + m] = run;
    run += t;
  }
  counts[m] = run;
}

__global__ __launch_bounds__(256) void rank_kernel(const int* __restrict__ id, int n,
                                                   const int* __restrict__ hist,
                                                   int* __restrict__ patch)
{
  __shared__ int lid[256];
  int t = threadIdx.x;
  int i = blockIdx.x*256 + t;
  lid[t] = (i < n) ? id[i] : -1;
  __syncthreads();
  if (i >= n) return;
  int m = lid[t];
  int r = hist[(long)blockIdx.x*NODES + m];
  for (int q = 0; q < t; ++q) r += (lid[q] == m) ? 1 : 0;
  if (r < KP) patch[m*KP + r] = i;
}

// ======================= generic fp32 GEMM core (coarse stack) =======================
__device__ __forceinline__ void gemm64_core(
    const float* __restrict__ W, const float* x1, const float* x2,
    const float* __restrict__ bias, const float* r, float* y,
    int O, int I, int I1, int N, int relu)
{
  int n0 = blockIdx.x * 64;
  int o0 = blockIdx.y * 64;
  int tid = threadIdx.x;
  int tx = tid & 15, ty = tid >> 4;

  __shared__ float Ws[16][68];
  __shared__ float Xs[16][68];

  float acc[4][4] = {};
  for (int k0 = 0; k0 < I; k0 += 16){
    {
      int e = tid * 4;
      int orow = e >> 4;
      int kcol = e & 15;
      float4 w4 = *reinterpret_cast<const float4*>(&W[(long)(o0 + orow) * I + k0 + kcol]);
      Ws[kcol+0][orow] = w4.x; Ws[kcol+1][orow] = w4.y;
      Ws[kcol+2][orow] = w4.z; Ws[kcol+3][orow] = w4.w;
    }
    {
      int e = tid * 4;
      int krow = e >> 6;
      int ncol = e & 63;
      int i = k0 + krow;
      const float* src = (i < I1) ? &x1[(long)i * N + n0 + ncol]
                                  : &x2[(long)(i - I1) * N + n0 + ncol];
      *reinterpret_cast<float4*>(&Xs[krow][ncol]) = *reinterpret_cast<const float4*>(src);
    }
    __syncthreads();
#pragma unroll
    for (int kk = 0; kk < 16; ++kk){
      float a[4], bb[4];
#pragma unroll
      for (int i2 = 0; i2 < 4; ++i2) a[i2] = Ws[kk][ty*4+i2];
#pragma unroll
      for (int j = 0; j < 4; ++j) bb[j] = Xs[kk][tx*4+j];
#pragma unroll
      for (int i2 = 0; i2 < 4; ++i2)
#pragma unroll
        for (int j = 0; j < 4; ++j)
          acc[i2][j] += a[i2]*bb[j];
    }
    __syncthreads();
  }
#pragma unroll
  for (int i2 = 0; i2 < 4; ++i2){
    int o = o0 + ty*4 + i2;
    float bv = bias[o];
#pragma unroll
    for (int j = 0; j < 4; ++j){
      int n = n0 + tx*4 + j;
      float v = acc[i2][j] + bv;
      if (r) v += r[(long)o * N + n];
      if (relu) v = fmaxf(v, 0.f);
      y[(long)o * N + n] = v;
    }
  }
}

__global__ __launch_bounds__(256) void gemm_f32(
    const float* __restrict__ W, const float* X1, const float* X2,
    const float* __restrict__ bias, const float* res, float* Y,
    int O, int I, int I1, int N,
    long sX1, long sX2, long sY, int relu)
{
  int b = blockIdx.z;
  gemm64_core(W, X1 + (long)b*sX1, X2 ? X2 + (long)b*sX2 : nullptr, bias,
              res ? res + (long)b*sY : nullptr, Y + (long)b*sY, O, I, I1, N, relu);
}

__global__ __launch_bounds__(256) void gemm_f32_qkv(
    const float* Xq, const float* Xkv,
    const float* Wq, const float* Wk, const float* Wv,
    const float* bq, const float* bk, const float* bv,
    float* oq, float* ok2, float* ov,
    int O, int I, int N)
{
  int which = blockIdx.z;
  const float* x1 = which ? Xkv : Xq;
  const float* W  = which==0 ? Wq : which==1 ? Wk : Wv;
  const float* bb = which==0 ? bq : which==1 ? bk : bv;
  float* y        = which==0 ? oq : which==1 ? ok2 : ov;
  gemm64_core(W, x1, nullptr, bb, nullptr, y, O, I, I, N, 0);
}

// C[b][n][m] = scale * sum_d A[b][d][n] * B[b][d][m]
__global__ __launch_bounds__(256) void gemm_tn(
    const float* __restrict__ A, const float* __restrict__ B, float* __restrict__ C,
    int Kd, int N, int Mc, int ldc, long sA, long sB, long sC, float scale)
{
  int b = blockIdx.z;
  const float* a = A + (long)b * sA;
  const float* bp = B + (long)b * sB;
  float* c = C + (long)b * sC;
  int m0 = blockIdx.x * 64, n0 = blockIdx.y * 64;
  int tid = threadIdx.x, tx = tid & 15, ty = tid >> 4;
  __shared__ float As[16][68], Bs[16][68];
  float acc[4][4] = {};
  for (int k0 = 0; k0 < Kd; k0 += 16){
    int e = tid * 4;
    int kr = e >> 6, nc = e & 63;
    *reinterpret_cast<float4*>(&As[kr][nc]) = *reinterpret_cast<const float4*>(&a[(long)(k0+kr)*N + n0 + nc]);
    *reinterpret_cast<float4*>(&Bs[kr][nc]) = *reinterpret_cast<const float4*>(&bp[(long)(k0+kr)*Mc + m0 + nc]);
    __syncthreads();
#pragma unroll
    for (int kk = 0; kk < 16; ++kk){
      float av[4], bv[4];
#pragma unroll
      for (int i = 0; i < 4; ++i) av[i] = As[kk][ty*4+i];
#pragma unroll
      for (int j = 0; j < 4; ++j) bv[j] = Bs[kk][tx*4+j];
#pragma unroll
      for (int i = 0; i < 4; ++i)
#pragma unroll
        for (int j = 0; j < 4; ++j) acc[i][j] += av[i]*bv[j];
    }
    __syncthreads();
  }
#pragma unroll
  for (int i = 0; i < 4; ++i)
#pragma unroll
    for (int j = 0; j < 4; ++j)
      c[(long)(n0 + ty*4 + i)*ldc + m0 + tx*4 + j] = acc[i][j] * scale;
}

// C[b][o][n] = sum_m P[b][o][m] * Q[b][n][m]
__global__ __launch_bounds__(256) void gemm_nt(
    const float* __restrict__ P, const float* __restrict__ Q, float* __restrict__ C,
    int O, int Nn, int Kd, long sP, long sQ, long sC)
{
  int b = blockIdx.z;
  const float* p = P + (long)b * sP;
  const float* q = Q + (long)b * sQ;
  float* c = C + (long)b * sC;
  int n0 = blockIdx.x * 64, o0 = blockIdx.y * 64;
  int tid = threadIdx.x, tx = tid & 15, ty = tid >> 4;
  __shared__ float Ps[64][20], Qs[64][20];
  float acc[4][4] = {};
  for (int k0 = 0; k0 < Kd; k0 += 16){
    int e = tid * 4;
    int row = e >> 4, col = e & 15;
    *reinterpret_cast<float4*>(&Ps[row][col]) = *reinterpret_cast<const float4*>(&p[(long)(o0+row)*Kd + k0 + col]);
    *reinterpret_cast<float4*>(&Qs[row][col]) = *reinterpret_cast<const float4*>(&q[(long)(n0+row)*Kd + k0 + col]);
    __syncthreads();
#pragma unroll
    for (int kk = 0; kk < 16; ++kk){
      float av[4], bv[4];
#pragma unroll
      for (int i = 0; i < 4; ++i) av[i] = Ps[ty*4+i][kk];
#pragma unroll
      for (int j = 0; j < 4; ++j) bv[j] = Qs[tx*4+j][kk];
#pragma unroll
      for (int i = 0; i < 4; ++i)
#pragma unroll
        for (int j = 0; j < 4; ++j) acc[i][j] += av[i]*bv[j];
    }
    __syncthreads();
  }
#pragma unroll
  for (int i = 0; i < 4; ++i)
#pragma unroll
    for (int j = 0; j < 4; ++j)
      c[(long)(o0 + ty*4 + i)*Nn + n0 + tx*4 + j] = acc[i][j];
}

__global__ __launch_bounds__(256) void softmax_rows(float* s, int nrows, int ncols)
{
  int row = blockIdx.x*4 + (threadIdx.x >> 6);
  if (row >= nrows) return;
  int lane = threadIdx.x & 63;
  float* p = s + (long)row * ncols;
  float mx = -INFINITY;
  for (int j = lane; j < ncols; j += 64) mx = fmaxf(mx, p[j]);
  for (int o = 32; o; o >>= 1) mx = fmaxf(mx, __shfl_xor(mx, o));
  float sum = 0.f;
  for (int j = lane; j < ncols; j += 64){ float e = expf(p[j]-mx); p[j]=e; sum+=e; }
  for (int o = 32; o; o >>= 1) sum += __shfl_xor(sum, o);
  for (int j = lane; j < ncols; j += 64) p[j] /= sum;
}

// ======================= bf16 MFMA GEMM (local stack, [n][d] row-major) =======================
// Y[64 rows][O cols] = relu( X[64][I] * W[O][I]^T * scale + bias + res ), all operands direct from L2.
__device__ __forceinline__ void mfma_tile64(
    const u16* __restrict__ X1, int I1,
    const u16* __restrict__ X2,
    const u16* __restrict__ W, int I,
    const float* __restrict__ bias,
    const u16* __restrict__ res,
    u16* outb, float* outf, int O,
    float scale, int relu)
{
  int wv_ = threadIdx.x >> 6;
  int o0 = (blockIdx.y << 6) + (wv_ << 4);
  int L  = threadIdx.x & 63;
  int lr = L & 15, lk = L >> 4;
  f32x4 acc[4] = {};
  const u16* wrow = W + (long)(o0 + lr) * I + 8*lk;
  for (int k0 = 0; k0 < I; k0 += 32){
    const u16* xs; int xstr, kk;
    if (k0 < I1){ xs = X1; xstr = I1; kk = k0; }
    else        { xs = X2; xstr = I - I1; kk = k0 - I1; }
    bf16x8 b = *(const bf16x8*)(wrow + k0);
    const u16* xp = xs + (long)lr * xstr + kk + 8*lk;
#pragma unroll
    for (int a = 0; a < 4; ++a){
      bf16x8 av = *(const bf16x8*)(xp + (long)(a<<4)*xstr);
      acc[a] = __builtin_amdgcn_mfma_f32_16x16x32_bf16(av, b, acc[a], 0, 0, 0);
    }
  }
  int col = o0 + lr;
  float bv = bias ? bias[col] : 0.f;
#pragma unroll
  for (int a = 0; a < 4; ++a){
#pragma unroll
    for (int q = 0; q < 4; ++q){
      int row = (a<<4) + (lk<<2) + q;
      float v = acc[a][q]*scale + bv;
      if (res)  v += b2f(res[(long)row*O + col]);
      if (relu) v = fmaxf(v, 0.f);
      if (outb) outb[(long)row*O + col] = f2b(v);
      else      outf[(long)row*O + col] = v;
    }
  }
}

__global__ __launch_bounds__(256) void mfma_gemm(
    const u16* X1, long x1z, const u16* X2, long x2z,
    const u16* W, long wz, const float* bias,
    const u16* res, long rz, u16* outb, float* outf, long oz,
    int O, int I, int I1, float scale, int relu)
{
  long z = blockIdx.z;
  mfma_tile64(X1 + z*x1z, I1, X2 ? X2 + z*x2z : nullptr,
              W + z*wz, I, bias,
              res ? res + z*rz : nullptr,
              outb ? outb + z*oz : nullptr,
              outf ? outf + z*oz : nullptr,
              O, scale, relu);
}

__global__ __launch_bounds__(256) void mfma_qkv(
    const u16* Xq, const u16* Xkv, long xz,
    const u16* Wq, const u16* Wk, const u16* Wv,
    const float* bq, const float* bk, const float* bv,
    u16* oq, u16* ok2, u16* ov, int O, int I)
{
  int which = blockIdx.z >> 8;
  long z = blockIdx.z & 255;
  const u16* X = (which ? Xkv : Xq) + z * xz;
  const u16* W = which==0 ? Wq : which==1 ? Wk : Wv;
  const float* bb = which==0 ? bq : which==1 ? bk : bv;
  u16* o = (which==0 ? oq : which==1 ? ok2 : ov) + z * (long)(64*O);
  mfma_tile64(X, I, nullptr, W, I, bb, nullptr, o, nullptr, O, 1.f, 0);
}

__global__ __launch_bounds__(256) void f2b_copy(const float* __restrict__ s,
                                                u16* __restrict__ d, int n)
{
  int i = blockIdx.x*256 + threadIdx.x;
  if (i < n) d[i] = f2b(s[i]);
}

// ======================= fused local attention (bf16 [n][d]) =======================
__global__ __launch_bounds__(256) void local_attn2(const u16* __restrict__ q,
                                                   const u16* __restrict__ k,
                                                   const u16* __restrict__ v,
                                                   u16* __restrict__ msg)
{
  int c = blockIdx.x >> 2, h = blockIdx.x & 3;
  long base = ((long)c*64)*128 + h*32;
  __shared__ float qs[64][33], ks[64][33], vs[64][33];
  __shared__ float ss[64][69];
  int tid = threadIdx.x;
  for (int e = tid; e < 2048; e += 256){
    int n = e >> 5, d = e & 31;
    long g = base + (long)n*128 + d;
    qs[n][d] = b2f(q[g]); ks[n][d] = b2f(k[g]); vs[n][d] = b2f(v[g]);
  }
  __syncthreads();
  const float SC = 0.17677669529663687f; // 1/sqrt(32)
  {
    int tx = tid & 15, ty = tid >> 4;
    float a[4][4] = {};
    for (int d = 0; d < 32; ++d){
      float qv[4], kv[4];
#pragma unroll
      for (int i = 0; i < 4; ++i){ qv[i] = qs[ty*4+i][d]; kv[i] = ks[tx*4+i][d]; }
#pragma unroll
      for (int i = 0; i < 4; ++i)
#pragma unroll
        for (int j = 0; j < 4; ++j) a[i][j] = fmaf(qv[i], kv[j], a[i][j]);
    }
#pragma unroll
    for (int i = 0; i < 4; ++i)
#pragma unroll
      for (int j = 0; j < 4; ++j) ss[ty*4+i][tx*4+j] = a[i][j]*SC;
  }
  __syncthreads();
  {
    int row = tid >> 2, sub = tid & 3;
    float mx = -INFINITY;
    for (int j = sub; j < 64; j += 4) mx = fmaxf(mx, ss[row][j]);
    mx = fmaxf(mx, __shfl_xor(mx, 1)); mx = fmaxf(mx, __shfl_xor(mx, 2));
    float sum = 0.f;
    for (int j = sub; j < 64; j += 4){ float e = __expf(ss[row][j]-mx); ss[row][j]=e; sum+=e; }
    sum += __shfl_xor(sum, 1); sum += __shfl_xor(sum, 2);
    float inv = 1.f/sum;
    for (int j = sub; j < 64; j += 4) ss[row][j] *= inv;
  }
  __syncthreads();
  {
    int dq = (tid & 7) * 4;
    int n0 = (tid >> 3) * 2;
    float a0[4] = {}, a1[4] = {};
    for (int m = 0; m < 64; ++m){
      float p0 = ss[n0][m], p1 = ss[n0+1][m];
      float w0 = vs[m][dq], w1 = vs[m][dq+1], w2 = vs[m][dq+2], w3 = vs[m][dq+3];
      a0[0]=fmaf(p0,w0,a0[0]); a0[1]=fmaf(p0,w1,a0[1]); a0[2]=fmaf(p0,w2,a0[2]); a0[3]=fmaf(p0,w3,a0[3]);
      a1[0]=fmaf(p1,w0,a1[0]); a1[1]=fmaf(p1,w1,a1[1]); a1[2]=fmaf(p1,w2,a1[2]); a1[3]=fmaf(p1,w3,a1[3]);
    }
    long g0 = base + (long)n0*128 + dq;
#pragma unroll
    for (int j = 0; j < 4; ++j) msg[g0 + j] = f2b(a0[j]);
#pragma unroll
    for (int j = 0; j < 4; ++j) msg[g0 + 128 + j] = f2b(a1[j]);
  }
}

// ======================= transport (exp-domain, doubly-shifted) =======================
__global__ __launch_bounds__(256) void fill_border(float* Z, const float* __restrict__ alpha)
{
  int i = blockIdx.x*256 + threadIdx.x;
  if (i < ZDIM){
    float a = alpha[0];
    Z[(long)i*ZDIM + (ZDIM-1)] = a;
    Z[(long)(ZDIM-1)*ZDIM + i] = a;
  }
}

__global__ __launch_bounds__(256) void transpose_k(const float* __restrict__ A,
                                                   float* __restrict__ B, int n)
{
  __shared__ float t[32][33];
  int bx = blockIdx.x*32, by = blockIdx.y*32;
  int lx = threadIdx.x & 31, ly0 = threadIdx.x >> 5;
  for (int dy = 0; dy < 32; dy += 8){
    int x = bx + lx, y = by + ly0 + dy;
    if (x < n && y < n) t[ly0+dy][lx] = A[(long)y*n + x];
  }
  __syncthreads();
  for (int dy = 0; dy < 32; dy += 8){
    int x = by + lx, y = bx + ly0 + dy;
    if (x < n && y < n) B[(long)y*n + x] = t[lx][ly0+dy];
  }
}

__global__ __launch_bounds__(64) void rowmax_k(const float* __restrict__ Z,
                                               const float* __restrict__ sub,
                                               float* __restrict__ out)
{
  int r = blockIdx.x;
  int lane = threadIdx.x;
  float m = -INFINITY;
  for (int j = lane; j < ZDIM; j += 64){
    float v = Z[(long)r*ZDIM + j];
    if (sub) v -= sub[j];
    m = fmaxf(m, v);
  }
  for (int o = 32; o; o >>= 1) m = fmaxf(m, __shfl_xor(m, o));
  if (lane == 0) out[r] = m;
}

__global__ __launch_bounds__(256) void expz_k(const float* __restrict__ Z,
                                              const float* __restrict__ Zt,
                                              const float* __restrict__ R,
                                              const float* __restrict__ C,
                                              float* __restrict__ eZ,
                                              float* __restrict__ eZT,
                                              float* __restrict__ wv)
{
  int i = blockIdx.x*256 + threadIdx.x;
  if (i < ZDIM) wv[i] = 1.f;
  if (i < ZDIM*ZDIM){
    int r = i / ZDIM, cc = i % ZDIM;
    eZ[i]  = expf(Z[i]  - R[r] - C[cc]);
    eZT[i] = expf(Zt[i] - C[r] - R[cc]);
  }
}

// wout[r] = EB(r) / sum_j E[r][j]*win[j]
__global__ __launch_bounds__(256) void tmatvec(const float* __restrict__ E,
                                               const float* __restrict__ win,
                                               float* __restrict__ wout,
                                               float ebm, float ebl)
{
  __shared__ float w4[4];
  int r = blockIdx.x;
  int tid = threadIdx.x;
  const float* e = E + (long)r * ZDIM;
  float dot = 0.f;
  for (int j = tid; j < ZDIM; j += 256) dot = fmaf(e[j], win[j], dot);
  for (int o = 32; o; o >>= 1) dot += __shfl_xor(dot, o);
  if ((tid & 63) == 0) w4[tid >> 6] = dot;
  __syncthreads();
  if (tid == 0){
    float s = w4[0] + w4[1] + w4[2] + w4[3];
    wout[r] = ((r < ZDIM-1) ? ebm : ebl) / s;
  }
}

__global__ __launch_bounds__(256) void uvfinal_k(const float* __restrict__ wu,
                                                 const float* __restrict__ wvv,
                                                 const float* __restrict__ R,
                                                 const float* __restrict__ C,
                                                 float* __restrict__ u,
                                                 float* __restrict__ v)
{
  int i = blockIdx.x*256 + threadIdx.x;
  if (i < ZDIM){
    u[i] = logf(wu[i]) - R[i];
    v[i] = logf(wvv[i]) - C[i];
  }
}

__global__ __launch_bounds__(256) void transport_out(const float* __restrict__ Z,
                                                     const float* __restrict__ u,
                                                     const float* __restrict__ v,
                                                     float norm, float* __restrict__ out)
{
  int idx = blockIdx.x*256 + threadIdx.x;
  if (idx >= ZDIM*ZDIM) return;
  int r = idx / ZDIM, c = idx % ZDIM;
  out[idx] = Z[idx] + u[r] + v[c] - norm;
}

// ======================= local gather (bf16 [c][n][d]) =======================
__global__ __launch_bounds__(256) void gather_feats(const float* __restrict__ F,
                                                    const int* __restrict__ patch,
                                                    const int* __restrict__ corr,
                                                    int side, u16* __restrict__ out)
{
  int c = blockIdx.x;
  __shared__ int sel[KP];
  int tid = threadIdx.x;
  if (tid < KP){
    int node = corr[c*2 + side];
    sel[tid] = patch[node*KP + tid];
  }
  __syncthreads();
  for (int e = tid; e < KP*DLOC; e += 256){
    int n = e >> 7, d = e & 127;
    out[((long)c*KP + n)*DLOC + d] = f2b(F[(long)sel[n]*DLOC + d]);
  }
}

// ======================= local sinkhorn (1024 threads) =======================
__global__ __launch_bounds__(1024) void sinkhorn_local(const float* __restrict__ lsraw,
                                                       const int* __restrict__ corr,
                                                       const int* __restrict__ cnt_s,
                                                       const int* __restrict__ cnt_t,
                                                       float* __restrict__ out)
{
  int c = blockIdx.x;
  int sn = corr[c*2], tn = corr[c*2+1];
  int cs = cnt_s[sn], ct = cnt_t[tn];
  __shared__ float la[65][73];   // stride 73 ≡ 9 (mod 32): conflict-free col access
  int tid = threadIdx.x;
  for (int e = tid; e < 65*65; e += 1024){
    int r = e / 65, col = e % 65;
    float v = 0.f;
    if (r < 64 && col < 64){
      v = lsraw[((long)c*64 + r)*64 + col];
      if (r >= cs || col >= ct) v = -1000000.0f;
    }
    la[r][col] = v;
  }
  __syncthreads();
  int g = tid >> 4, sub = tid & 15;
  for (int it = 0; it < 50; ++it){
    // rows 0..63 over 65 cols
    {
      float mx = -INFINITY;
      for (int j = sub; j < 65; j += 16) mx = fmaxf(mx, la[g][j]);
      mx = fmaxf(mx, __shfl_xor(mx, 1)); mx = fmaxf(mx, __shfl_xor(mx, 2));
      mx = fmaxf(mx, __shfl_xor(mx, 4)); mx = fmaxf(mx, __shfl_xor(mx, 8));
      float s = 0.f;
      for (int j = sub; j < 65; j += 16) s += __expf(la[g][j]-mx);
      s += __shfl_xor(s, 1); s += __shfl_xor(s, 2);
      s += __shfl_xor(s, 4); s += __shfl_xor(s, 8);
      float lse = mx + __logf(s);
      for (int j = sub; j < 65; j += 16) la[g][j] -= lse;
    }
    __syncthreads();
    // cols 0..63 over 65 rows
    {
      float mx = -INFINITY;
      for (int rr = sub; rr < 65; rr += 16) mx = fmaxf(mx, la[rr][g]);
      mx = fmaxf(mx, __shfl_xor(mx, 1)); mx = fmaxf(mx, __shfl_xor(mx, 2));
      mx = fmaxf(mx, __shfl_xor(mx, 4)); mx = fmaxf(mx, __shfl_xor(mx, 8));
      float s = 0.f;
      for (int rr = sub; rr < 65; rr += 16) s += __expf(la[rr][g]-mx);
      s += __shfl_xor(s, 1); s += __shfl_xor(s, 2);
      s += __shfl_xor(s, 4); s += __shfl_xor(s, 8);
      float lse = mx + __logf(s);
      for (int rr = sub; rr < 65; rr += 16) la[rr][g] -= lse;
    }
    __syncthreads();
  }
  for (int e = tid; e < 65*65; e += 1024)
    out[(long)c*4225 + e] = la[e/65][e%65];
}

// ======================= GT (unchanged — decision-exact) =======================
__global__ __launch_bounds__(256) void gt_kernel(const float* __restrict__ sraw,
                                                 const float* __restrict__ traw,
                                                 const float* __restrict__ rot,
                                                 const float* __restrict__ trans,
                                                 const int* __restrict__ patch_s,
                                                 const int* __restrict__ patch_t,
                                                 const int* __restrict__ corr,
                                                 const int* __restrict__ cnt_s,
                                                 const int* __restrict__ cnt_t,
                                                 float* __restrict__ out)
{
#pragma clang fp contract(off)
  int c = blockIdx.x, tid = threadIdx.x;
  int sn = corr[c*2], tn = corr[c*2+1];
  int cs = cnt_s[sn], ct = cnt_t[tn];
  __shared__ float sx[64], sy[64], sz[64], spp[64];
  __shared__ float txa[64], tya[64], tza[64], tpp[64];
  __shared__ float g[64][65];
  __shared__ float rowsum[64], colsum[64];
  if (tid < 64){
    int idx = patch_s[sn*KP + tid];
    float p0 = sraw[(long)idx*3], p1 = sraw[(long)idx*3+1], p2 = sraw[(long)idx*3+2];
    float a0 = fmaf(rot[2], p2, fmaf(rot[1], p1, rot[0]*p0)) + trans[0];
    float a1 = fmaf(rot[5], p2, fmaf(rot[4], p1, rot[3]*p0)) + trans[1];
    float a2 = fmaf(rot[8], p2, fmaf(rot[7], p1, rot[6]*p0)) + trans[2];
    sx[tid]=a0; sy[tid]=a1; sz[tid]=a2;
    spp[tid] = a0*a0 + a1*a1 + a2*a2;
  } else if (tid < 128){
    int l = tid - 64;
    int idx = patch_t[tn*KP + l];
    float p0 = traw[(long)idx*3], p1 = traw[(long)idx*3+1], p2 = traw[(long)idx*3+2];
    txa[l]=p0; tya[l]=p1; tza[l]=p2;
    tpp[l] = p0*p0 + p1*p1 + p2*p2;
  }
  __syncthreads();
  for (int e = tid; e < 4096; e += 256){
    int n = e >> 6, m = e & 63;
    float dot = fmaf(sz[n], tza[m], fmaf(sy[n], tya[m], sx[n]*txa[m]));
    float d2 = (spp[n] + tpp[m]) - 2.0f*dot;
    d2 = fmaxf(d2, 0.f);
    g[n][m] = (sqrtf(d2) < 0.1f) ? 1.f : 0.f;
  }
  __syncthreads();
  if (tid < 64){
    float s = 0.f;
    for (int m = 0; m < 64; ++m) s += g[tid][m];
    rowsum[tid] = fmaxf(1.f - s, 0.f);
  } else if (tid < 128){
    int m = tid - 64;
    float s = 0.f;
    for (int n = 0; n < 64; ++n) s += g[n][m];
    colsum[m] = fmaxf(1.f - s, 0.f);
  }
  __syncthreads();
  float* o = out + (long)c*4225;
  for (int e = tid; e < 4225; e += 256){
    int r = e / 65, col = e % 65;
    float v;
    if (r < 64 && col < 64) v = g[r][col];
    else if (r < 64)        v = rowsum[r];
    else if (col < 64)      v = colsum[col];
    else                    v = 0.f;
    if (r < 64 && r >= cs)    v = 0.f;
    if (col < 64 && col >= ct) v = 0.f;
    o[e] = v;
  }
}

// ======================= host =======================
extern "C" void kernel_launch(void* const* d_in, const int* in_sizes, int n_in,
                              void* d_out, int out_size, void* d_ws, size_t ws_size,
                              hipStream_t stream)
{
  const float* src_pcd_c  = (const float*)d_in[0];
  const float* tgt_pcd_c  = (const float*)d_in[1];
  const float* src_node_c = (const float*)d_in[2];
  const float* tgt_node_c = (const float*)d_in[3];
  const float* src_feats  = (const float*)d_in[4];
  const float* tgt_feats  = (const float*)d_in[5];
  const float* src_final  = (const float*)d_in[6];
  const float* tgt_final  = (const float*)d_in[7];
  const float* rot        = (const float*)d_in[8];
  const float* trans      = (const float*)d_in[9];
  const float* src_raw    = (const float*)d_in[10];
  const float* tgt_raw    = (const float*)d_in[11];
  const int*   node_corr  = (const int*)d_in[12];
  const float* c_wq = (const float*)d_in[13]; const float* c_bq = (const float*)d_in[14];
  const float* c_wk = (const float*)d_in[15]; const float* c_bk = (const float*)d_in[16];
  const float* c_wv = (const float*)d_in[17]; const float* c_bv = (const float*)d_in[18];
  const float* c_wm = (const float*)d_in[19]; const float* c_bm = (const float*)d_in[20];
  const float* c_w1 = (const float*)d_in[21]; const float* c_b1 = (const float*)d_in[22];
  const float* c_w2 = (const float*)d_in[23]; const float* c_b2 = (const float*)d_in[24];
  const float* l_wq = (const float*)d_in[25]; const float* l_bq = (const float*)d_in[26];
  const float* l_wk = (const float*)d_in[27]; const float* l_bk = (const float*)d_in[28];
  const float* l_wv = (const float*)d_in[29]; const float* l_bv = (const float*)d_in[30];
  const float* l_wm = (const float*)d_in[31]; const float* l_bm = (const float*)d_in[32];
  const float* l_w1 = (const float*)d_in[33]; const float* l_b1 = (const float*)d_in[34];
  const float* l_w2 = (const float*)d_in[35]; const float* l_b2 = (const float*)d_in[36];
  const float* fp_w = (const float*)d_in[37]; const float* fp_b = (const float*)d_in[38];
  const float* lfp_w = (const float*)d_in[39]; const float* lfp_b = (const float*)d_in[40];
  const float* bin_score = (const float*)d_in[41];

  const int NS = in_sizes[0] / 3;
  const int NT = in_sizes[1] / 3;

  float* FB = (float*)d_ws;

  // ---- coarse/transport overlay region: [0, 4M floats) ----
  size_t coff = 0;
  auto calloc2 = [&](size_t n){ float* p = FB + coff; coff += (n + 63) & ~size_t(63); return p; };
  float* sf   = calloc2(DC*MCT);
  float* tf   = calloc2(DC*MCT);
  float* cq   = calloc2(DC*MCT);
  float* ck   = calloc2(DC*MCT);
  float* cv   = calloc2(DC*MCT);
  float* cs   = calloc2(4*MCT*MCT);
  float* cmsg = calloc2(DC*MCT);
  float* cmsg2= calloc2(DC*MCT);
  float* ch1  = calloc2(2*DC*MCT);
  float* sfp  = calloc2(DC*MCT);
  float* tfp  = calloc2(DC*MCT);
  float* Zx   = calloc2(ZDIM*ZDIM);
  float* Zt   = calloc2(ZDIM*ZDIM);
  float* eZ   = calloc2(ZDIM*ZDIM);
  float* eZT  = calloc2(ZDIM*ZDIM);
  float* Rr   = calloc2(640);
  float* Cc   = calloc2(640);
  float* wu   = calloc2(640);
  float* wv   = calloc2(640);
  float* uu   = calloc2(640);
  float* vv   = calloc2(640);

  // ---- local region: from 4M floats ----
  size_t off = 4*1024*1024;
  auto falloc = [&](size_t n){ float* p = FB + off; off += (n + 63) & ~size_t(63); return p; };
  u16* spf  = (u16*)falloc(1048576);   // [256][64][128] bf16 (tpf must follow contiguously)
  u16* tpf  = (u16*)falloc(1048576);
  u16* lq   = (u16*)falloc(1048576);   // lk must follow contiguously
  u16* lk   = (u16*)falloc(1048576);
  u16* lv   = (u16*)falloc(1048576);
  u16* lmsg = (u16*)falloc(1048576);
  u16* lh1  = (u16*)falloc(2097152);   // [256][64][256] bf16
  float* lsraw = falloc(1048576);      // [256][64][64] fp32
  u16* wqb = (u16*)falloc(24576);      // 3*128*128 bf16
  u16* wkb = (u16*)falloc(24576);
  u16* wvb = (u16*)falloc(24576);
  u16* wmb = (u16*)falloc(24576);
  u16* w1b = (u16*)falloc(98304);      // 3*256*256
  u16* w2b = (u16*)falloc(49152);      // 3*128*256
  u16* lfpb= (u16*)falloc(8192);       // 128*128

  // ---- int region ----
  int* IB = (int*)(FB + off);
  size_t ioff = 0;
  auto ialloc = [&](size_t n){ int* p = IB + ioff; ioff += (n + 63) & ~size_t(63); return p; };
  int* id_s = ialloc(NS);
  int* id_t = ialloc(NT);
  const int nbs = (NS + 255) / 256, nbt = (NT + 255) / 256;
  int* hist_s = ialloc((size_t)nbs * NODES);
  int* hist_t = ialloc((size_t)nbt * NODES);
  int* cnt_s = ialloc(NODES);
  int* cnt_t = ialloc(NODES);
  int* patch_s = ialloc(NODES*KP);
  int* patch_t = ialloc(NODES*KP);

  float* out0 = (float*)d_out;
  float* out_ls = out0 + ZDIM*ZDIM;
  float* out_gt = out_ls + (long)CC*65*65;

  // ---- phase 0: local weights -> bf16 ----
  f2b_copy<<<(3*128*128+255)/256, 256, 0, stream>>>(l_wq, wqb, 3*128*128);
  f2b_copy<<<(3*128*128+255)/256, 256, 0, stream>>>(l_wk, wkb, 3*128*128);
  f2b_copy<<<(3*128*128+255)/256, 256, 0, stream>>>(l_wv, wvb, 3*128*128);
  f2b_copy<<<(3*128*128+255)/256, 256, 0, stream>>>(l_wm, wmb, 3*128*128);
  f2b_copy<<<(3*256*256+255)/256, 256, 0, stream>>>(l_w1, w1b, 3*256*256);
  f2b_copy<<<(3*128*256+255)/256, 256, 0, stream>>>(l_w2, w2b, 3*128*256);
  f2b_copy<<<(128*128+255)/256, 256, 0, stream>>>(lfp_w, lfpb, 128*128);

  // ---- phase 1: NN + patches ----
  nn_kernel<<<nbs, 256, 0, stream>>>(src_pcd_c, NS, src_node_c, id_s);
  nn_kernel<<<nbt, 256, 0, stream>>>(tgt_pcd_c, NT, tgt_node_c, id_t);
  hist_kernel<<<nbs, 256, 0, stream>>>(id_s, NS, hist_s);
  hist_kernel<<<nbt, 256, 0, stream>>>(id_t, NT, hist_t);
  scan_kernel<<<1, 512, 0, stream>>>(hist_s, nbs, cnt_s);
  scan_kernel<<<1, 512, 0, stream>>>(hist_t, nbt, cnt_t);
  hipMemsetAsync(patch_s, 0, NODES*KP*sizeof(int), stream);
  hipMemsetAsync(patch_t, 0, NODES*KP*sizeof(int), stream);
  rank_kernel<<<nbs, 256, 0, stream>>>(id_s, NS, hist_s, patch_s);
  rank_kernel<<<nbt, 256, 0, stream>>>(id_t, NT, hist_t, patch_t);

  // ---- phase 2: coarse transformer (fp32) ----
  hipMemcpyAsync(sf, src_feats, DC*MCT*sizeof(float), hipMemcpyDeviceToDevice, stream);
  hipMemcpyAsync(tf, tgt_feats, DC*MCT*sizeof(float), hipMemcpyDeviceToDevice, stream);

  auto gemm = [&](const float* W, const float* X1, const float* X2, const float* bias,
                  const float* res, float* Y, int O, int I, int I1, int N,
                  long sX, long sY, int batch, int relu){
    dim3 g(N/64, O/64, batch);
    gemm_f32<<<g, 256, 0, stream>>>(W, X1, X2, bias, res, Y, O, I, I1, N, sX, sX, sY, relu);
  };

  auto coarse_block = [&](int l, float* x, float* srcb){
    const float* wq = c_wq + (size_t)l*DC*DC; const float* bq = c_bq + (size_t)l*DC;
    const float* wk = c_wk + (size_t)l*DC*DC; const float* bk = c_bk + (size_t)l*DC;
    const float* wvp = c_wv + (size_t)l*DC*DC; const float* bv = c_bv + (size_t)l*DC;
    const float* wm = c_wm + (size_t)l*DC*DC; const float* bm = c_bm + (size_t)l*DC;
    const float* w1 = c_w1 + (size_t)l*4*DC*DC; const float* b1 = c_b1 + (size_t)l*2*DC;
    const float* w2 = c_w2 + (size_t)l*2*DC*DC; const float* b2 = c_b2 + (size_t)l*DC;
    gemm_f32_qkv<<<dim3(MCT/64, DC/64, 3), 256, 0, stream>>>(
        x, srcb, wq, wk, wvp, bq, bk, bv, cq, ck, cv, DC, DC, MCT);
    gemm_tn<<<dim3(8,8,4), 256, 0, stream>>>(cq, ck, cs, 64, MCT, MCT, MCT,
                                             (long)64*MCT, (long)64*MCT, (long)MCT*MCT, 0.125f);
    softmax_rows<<<(4*MCT)/4, 256, 0, stream>>>(cs, 4*MCT, MCT);
    gemm_nt<<<dim3(8,1,4), 256, 0, stream>>>(cv, cs, cmsg, 64, MCT, MCT,
                                             (long)64*MCT, (long)MCT*MCT, (long)64*MCT);
    gemm(wm, cmsg, nullptr, bm, nullptr, cmsg2, DC, DC, DC, MCT, 0, 0, 1, 0);
    gemm(w1, x, cmsg2, b1, nullptr, ch1, 2*DC, 2*DC, DC, MCT, 0, 0, 1, 1);
    gemm(w2, ch1, nullptr, b2, x, x, DC, 2*DC, 2*DC, MCT, 0, 0, 1, 0);
  };
  coarse_block(0, sf, sf);
  coarse_block(0, tf, tf);
  coarse_block(1, sf, tf);
  coarse_block(1, tf, sf);
  coarse_block(2, sf, sf);
  coarse_block(2, tf, tf);

  // fp projections (batched z=2: sf->sfp, tf->tfp; contiguous allocations)
  gemm(fp_w, sf, nullptr, fp_b, nullptr, sfp, DC, DC, DC, MCT, (long)DC*MCT, (long)DC*MCT, 2, 0);
  gemm_tn<<<dim3(8,8,1), 256, 0, stream>>>(sfp, tfp, Zx, DC, MCT, MCT, ZDIM,
                                           0L, 0L, 0L, 0.0625f);
  fill_border<<<3, 256, 0, stream>>>(Zx, bin_score);

  // ---- transport: exp-domain sinkhorn ----
  transpose_k<<<dim3(17,17), 256, 0, stream>>>(Zx, Zt, ZDIM);
  rowmax_k<<<ZDIM, 64, 0, stream>>>(Zx, nullptr, Rr);
  rowmax_k<<<ZDIM, 64, 0, stream>>>(Zt, Rr, Cc);
  expz_k<<<(ZDIM*ZDIM + 255)/256, 256, 0, stream>>>(Zx, Zt, Rr, Cc, eZ, eZT, wv);
  const float EBM = 1.0f/1024.0f, EBL = 0.5f;
  for (int it = 0; it < 50; ++it){
    tmatvec<<<ZDIM, 256, 0, stream>>>(eZ,  wv, wu, EBM, EBL);
    tmatvec<<<ZDIM, 256, 0, stream>>>(eZT, wu, wv, EBM, EBL);
  }
  uvfinal_k<<<(ZDIM+255)/256, 256, 0, stream>>>(wu, wv, Rr, Cc, uu, vv);
  const float NORM = (float)(-log(1024.0));
  transport_out<<<(ZDIM*ZDIM + 255)/256, 256, 0, stream>>>(Zx, uu, vv, NORM, out0);

  // ---- phase 3: local transformer (bf16 MFMA, [c][n][d]) ----
  gather_feats<<<CC, 256, 0, stream>>>(src_final, patch_s, node_corr, 0, spf);
  gather_feats<<<CC, 256, 0, stream>>>(tgt_final, patch_t, node_corr, 1, tpf);

  const long ZF = 64*128;   // per-patch activation stride (elems)
  const long ZH = 64*256;
  auto local_block = [&](int l, u16* x, u16* srcb){
    const u16* wq = wqb + (size_t)l*128*128; const float* bq = l_bq + (size_t)l*128;
    const u16* wk2 = wkb + (size_t)l*128*128; const float* bk = l_bk + (size_t)l*128;
    const u16* wv2 = wvb + (size_t)l*128*128; const float* bv = l_bv + (size_t)l*128;
    const u16* wm = wmb + (size_t)l*128*128; const float* bm = l_bm + (size_t)l*128;
    const u16* w1 = w1b + (size_t)l*256*256; const float* b1 = l_b1 + (size_t)l*256;
    const u16* w2 = w2b + (size_t)l*128*256; const float* b2 = l_b2 + (size_t)l*128;
    mfma_qkv<<<dim3(1,2,3*CC), 256, 0, stream>>>(x, srcb, ZF, wq, wk2, wv2,
                                                 bq, bk, bv, lq, lk, lv, 128, 128);
    local_attn2<<<CC*4, 256, 0, stream>>>(lq, lk, lv, lmsg);
    mfma_gemm<<<dim3(1,2,CC), 256, 0, stream>>>(lmsg, ZF, nullptr, 0, wm, 0, bm,
                                                nullptr, 0, lq, nullptr, ZF, 128, 128, 128, 1.f, 0);
    mfma_gemm<<<dim3(1,4,CC), 256, 0, stream>>>(x, ZF, lq, ZF, w1, 0, b1,
                                                nullptr, 0, lh1, nullptr, ZH, 256, 256, 128, 1.f, 1);
    mfma_gemm<<<dim3(1,2,CC), 256, 0, stream>>>(lh1, ZH, nullptr, 0, w2, 0, b2,
                                                x, ZF, x, nullptr, ZF, 128, 256, 256, 1.f, 0);
  };
  local_block(0, spf, spf);
  local_block(0, tpf, tpf);
  local_block(1, spf, tpf);
  local_block(1, tpf, spf);
  local_block(2, spf, spf);
  local_block(2, tpf, tpf);

  // lfp projection: z=512 spans spf+tpf -> lq+lk (contiguous)
  mfma_gemm<<<dim3(1,2,2*CC), 256, 0, stream>>>(spf, ZF, nullptr, 0, lfpb, 0, lfp_b,
                                                nullptr, 0, lq, nullptr, ZF, 128, 128, 128, 1.f, 0);
  // scores: lsraw[c][n][m] = lq[c]·lk[c]^T / sqrt(128)
  mfma_gemm<<<dim3(1,1,CC), 256, 0, stream>>>(lq, ZF, nullptr, 0, lk, ZF, nullptr,
                                              nullptr, 0, nullptr, lsraw, (long)64*64,
                                              64, 128, 128, 0.08838834764831845f, 0);
  sinkhorn_local<<<CC, 1024, 0, stream>>>(lsraw, node_corr, cnt_s, cnt_t, out_ls);

  // ---- phase 4: GT ----
  gt_kernel<<<CC, 256, 0, stream>>>(src_raw, tgt_raw, rot, trans,
                                    patch_s, patch_t, node_corr, cnt_s, cnt_t, out_gt);

  (void)n_in; (void)out_size; (void)ws_size; (void)tgt_feats;
}

// Round 3
// 1331.778 us; speedup vs baseline: 2.3689x; 1.7204x over previous
//
#include <hip/hip_runtime.h>
#include <math.h>

static constexpr int NODES = 512;
static constexpr int CC    = 256;
static constexpr int KP    = 64;
static constexpr int ZDIM  = 513;

typedef unsigned short u16;
typedef short bf16x8 __attribute__((ext_vector_type(8)));
typedef float f32x4 __attribute__((ext_vector_type(4)));

__device__ __forceinline__ u16 f2b(float f){
  unsigned u = __float_as_uint(f);
  unsigned r = (u + 0x7FFF + ((u >> 16) & 1)) >> 16;
  return (u16)r;
}
__device__ __forceinline__ float b2f(u16 h){ return __uint_as_float(((unsigned)h) << 16); }
__device__ __forceinline__ f32x4 mfma16(bf16x8 a, bf16x8 b, f32x4 c){
  return __builtin_amdgcn_mfma_f32_16x16x32_bf16(a, b, c, 0, 0, 0);
}

// ======================= NN + patches (decision-exact) =======================
__global__ __launch_bounds__(256) void nn_kernel(const float* __restrict__ pts, int n,
                                                 const float* __restrict__ nodes,
                                                 int* __restrict__ out)
{
#pragma clang fp contract(off)
  __shared__ float nx[NODES], ny[NODES], nz[NODES], nn[NODES];
  for (int m = threadIdx.x; m < NODES; m += 256){
    float a = nodes[m*3+0], b = nodes[m*3+1], c = nodes[m*3+2];
    nx[m]=a; ny[m]=b; nz[m]=c;
    nn[m] = a*a + b*b + c*c;
  }
  __syncthreads();
  int i = blockIdx.x*256 + threadIdx.x;
  if (i >= n) return;
  float p0 = pts[i*3+0], p1 = pts[i*3+1], p2 = pts[i*3+2];
  float pp = p0*p0 + p1*p1 + p2*p2;
  float best = INFINITY; int bi = 0;
  for (int m = 0; m < NODES; ++m){
    float dot = fmaf(p2, nz[m], fmaf(p1, ny[m], p0*nx[m]));
    float d = (pp - 2.0f*dot) + nn[m];
    if (d < best){ best = d; bi = m; }
  }
  out[i] = bi;
}

__global__ __launch_bounds__(256) void hist_kernel(const int* __restrict__ id, int n,
                                                   int* __restrict__ hist)
{
  __shared__ int h[NODES];
  int t = threadIdx.x;
  h[t] = 0; h[t+256] = 0;
  __syncthreads();
  int i = blockIdx.x*256 + t;
  if (i < n) atomicAdd(&h[id[i]], 1);
  __syncthreads();
  hist[(long)blockIdx.x*NODES + t]       = h[t];
  hist[(long)blockIdx.x*NODES + t + 256] = h[t+256];
}

__global__ __launch_bounds__(512) void scan_kernel(int* __restrict__ hist, int nb,
                                                   int* __restrict__ counts)
{
  int m = threadIdx.x;
  int run = 0;
  for (int b = 0; b < nb; ++b){
    int t = hist[(long)b*NODES + m];
    hist[(long)b*NODES + m] = run;
    run += t;
  }
  counts[m] = run;
}

__global__ __launch_bounds__(256) void rank_kernel(const int* __restrict__ id, int n,
                                                   const int* __restrict__ hist,
                                                   int* __restrict__ patch)
{
  __shared__ int lid[256];
  int t = threadIdx.x;
  int i = blockIdx.x*256 + t;
  lid[t] = (i < n) ? id[i] : -1;
  __syncthreads();
  if (i >= n) return;
  int m = lid[t];
  int r = hist[(long)blockIdx.x*NODES + m];
  for (int q = 0; q < t; ++q) r += (lid[q] == m) ? 1 : 0;
  if (r < KP) patch[m*KP + r] = i;
}

// ======================= weight conversion (all bf16 weights, one kernel) =======================
__global__ __launch_bounds__(256) void conv_weights(
  const float* cwq, const float* cwk, const float* cwv, const float* cwm,
  const float* cw1, const float* cw2, const float* fpw,
  const float* lwq, const float* lwk, const float* lwv, const float* lwm,
  const float* lw1, const float* lw2, const float* lfp,
  u16* __restrict__ dst)
{
  int i = blockIdx.x*256 + threadIdx.x;
  if (i >= 2539520) return;
  const float* s; int off;
  if      (i <  196608){ s=cwq; off=0; }
  else if (i <  393216){ s=cwk; off=196608; }
  else if (i <  589824){ s=cwv; off=393216; }
  else if (i <  786432){ s=cwm; off=589824; }
  else if (i < 1572864){ s=cw1; off=786432; }
  else if (i < 1966080){ s=cw2; off=1572864; }
  else if (i < 2031616){ s=fpw; off=1966080; }
  else if (i < 2080768){ s=lwq; off=2031616; }
  else if (i < 2129920){ s=lwk; off=2080768; }
  else if (i < 2179072){ s=lwv; off=2129920; }
  else if (i < 2228224){ s=lwm; off=2179072; }
  else if (i < 2424832){ s=lw1; off=2228224; }
  else if (i < 2523136){ s=lw2; off=2424832; }
  else                 { s=lfp; off=2523136; }
  dst[i] = f2b(s[i - off]);
}

// cf[side][n][d] (bf16) + cff (fp32 residual stream) from feats [side][d][n]
__global__ __launch_bounds__(256) void tr_in(const float* __restrict__ fs,
                                             const float* __restrict__ ft,
                                             u16* __restrict__ cf,
                                             float* __restrict__ cff)
{
  int i = blockIdx.x*256 + threadIdx.x;
  if (i >= 262144) return;
  int side = i >> 17; int r = i & 131071; int d = r >> 9; int n = r & 511;
  float v = (side ? ft : fs)[r];
  long o = ((long)side*512 + n)*256 + d;
  cf[o] = f2b(v);
  cff[o] = v;
}

// ======================= coarse transformer (bf16 MFMA, [n][d]) =======================
// qkv: grid 24*nsides: z -> side=side0+z/24, rem=z%24, proj=rem>>3, slice=rem&7
__global__ __launch_bounds__(256) void coarse_qkv(
    const u16* __restrict__ cf, int cross, int side0,
    const u16* __restrict__ Wq, const u16* __restrict__ Wk, const u16* __restrict__ Wv,
    const float* __restrict__ bq, const float* __restrict__ bk, const float* __restrict__ bv,
    u16* __restrict__ qb, u16* __restrict__ kb, u16* __restrict__ vtb)
{
  int z = blockIdx.x;
  int side = side0 + z/24, rem = z%24, proj = rem >> 3, slice = rem & 7;
  const u16* x = cf + (long)side*131072;
  const u16* s = cross ? cf + (long)(1-side)*131072 : x;
  const u16* in = (proj == 0) ? x : s;
  const u16* W  = (proj==0)?Wq:(proj==1)?Wk:Wv;
  const float* bi = (proj==0)?bq:(proj==1)?bk:bv;
  int n0 = slice << 6;
  int wv_ = threadIdx.x >> 6, L = threadIdx.x & 63, lr = L & 15, lk = L >> 4;
  const u16* inb = in + (long)(n0 + lr)*256 + 8*lk;
  for (int oi = 0; oi < 4; ++oi){
    int o0 = (wv_*4 + oi) << 4;
    const u16* wrow = W + (long)(o0 + lr)*256 + 8*lk;
    f32x4 acc[4] = {};
#pragma unroll
    for (int ks = 0; ks < 8; ++ks){
      bf16x8 b = *(const bf16x8*)(wrow + ks*32);
#pragma unroll
      for (int a = 0; a < 4; ++a){
        bf16x8 av = *(const bf16x8*)(inb + a*16*256 + ks*32);
        acc[a] = mfma16(av, b, acc[a]);
      }
    }
    int col = o0 + lr;
    float bvv = bi[col];
    if (proj < 2){
      u16* o = (proj==0 ? qb : kb) + ((long)side*512 + n0)*256 + col;
#pragma unroll
      for (int a = 0; a < 4; ++a)
#pragma unroll
        for (int q_ = 0; q_ < 4; ++q_)
          o[(long)(a*16 + lk*4 + q_)*256] = f2b(acc[a][q_] + bvv);
    } else {
      u16* o = vtb + ((long)side*256 + col)*512 + n0;
#pragma unroll
      for (int a = 0; a < 4; ++a)
#pragma unroll
        for (int q_ = 0; q_ < 4; ++q_)
          o[a*16 + lk*4 + q_] = f2b(acc[a][q_] + bvv);
    }
  }
}

// attn: grid 32*nsides: z -> side=side0+z/32, rem: head=(rem>>3), qs=rem&7
__global__ __launch_bounds__(256) void coarse_attn(
    const u16* __restrict__ qb, const u16* __restrict__ kb,
    const u16* __restrict__ vtb, u16* __restrict__ msgb, int side0)
{
  __shared__ u16 P[64][512];
  __shared__ float rmx[64][4], rsm[64][4];
  int z = blockIdx.x;
  int side = side0 + (z >> 5); int rem = z & 31;
  int head = rem >> 3, qs = rem & 7;
  int wv_ = threadIdx.x >> 6, L = threadIdx.x & 63, lr = L & 15, lk = L >> 4;
  const u16* q = qb + ((long)side*512 + qs*64)*256 + head*64;
  const u16* k = kb + (long)side*512*256 + head*64;
  const u16* vt = vtb + ((long)side*256 + head*64)*512;

  bf16x8 af[4][2];
#pragma unroll
  for (int a = 0; a < 4; ++a)
#pragma unroll
    for (int ks = 0; ks < 2; ++ks)
      af[a][ks] = *(const bf16x8*)(q + (long)(a*16 + lr)*256 + ks*32 + 8*lk);

  f32x4 sc[4][8] = {};
  for (int b = 0; b < 8; ++b){
    const u16* krow = k + (long)(wv_*128 + b*16 + lr)*256 + 8*lk;
#pragma unroll
    for (int ks = 0; ks < 2; ++ks){
      bf16x8 bf = *(const bf16x8*)(krow + ks*32);
#pragma unroll
      for (int a = 0; a < 4; ++a)
        sc[a][b] = mfma16(af[a][ks], bf, sc[a][b]);
    }
  }
  const float SC = 0.125f; // 1/sqrt(64)
#pragma unroll
  for (int a = 0; a < 4; ++a)
#pragma unroll
    for (int q_ = 0; q_ < 4; ++q_){
      float m = sc[a][0][q_];
#pragma unroll
      for (int b = 1; b < 8; ++b) m = fmaxf(m, sc[a][b][q_]);
      m = fmaxf(m, __shfl_xor(m, 1)); m = fmaxf(m, __shfl_xor(m, 2));
      m = fmaxf(m, __shfl_xor(m, 4)); m = fmaxf(m, __shfl_xor(m, 8));
      if (lr == 0) rmx[a*16 + lk*4 + q_][wv_] = m;
    }
  __syncthreads();
#pragma unroll
  for (int a = 0; a < 4; ++a)
#pragma unroll
    for (int q_ = 0; q_ < 4; ++q_){
      int row = a*16 + lk*4 + q_;
      float m = fmaxf(fmaxf(rmx[row][0], rmx[row][1]), fmaxf(rmx[row][2], rmx[row][3]));
      float s = 0.f;
#pragma unroll
      for (int b = 0; b < 8; ++b){
        float e = __expf((sc[a][b][q_] - m)*SC);
        sc[a][b][q_] = e; s += e;
      }
      s += __shfl_xor(s,1); s += __shfl_xor(s,2); s += __shfl_xor(s,4); s += __shfl_xor(s,8);
      if (lr == 0) rsm[row][wv_] = s;
    }
  __syncthreads();
#pragma unroll
  for (int a = 0; a < 4; ++a)
#pragma unroll
    for (int q_ = 0; q_ < 4; ++q_){
      int row = a*16 + lk*4 + q_;
      float inv = 1.f / (rsm[row][0]+rsm[row][1]+rsm[row][2]+rsm[row][3]);
#pragma unroll
      for (int b = 0; b < 8; ++b)
        P[row][wv_*128 + b*16 + lr] = f2b(sc[a][b][q_] * inv);
    }
  __syncthreads();
  f32x4 mv[4] = {};
  for (int ks = 0; ks < 16; ++ks){
    bf16x8 bf = *(const bf16x8*)(vt + (long)(wv_*16 + lr)*512 + ks*32 + 8*lk);
#pragma unroll
    for (int a = 0; a < 4; ++a){
      bf16x8 av = *(const bf16x8*)(&P[a*16 + lr][ks*32 + 8*lk]);
      mv[a] = mfma16(av, bf, mv[a]);
    }
  }
  u16* o = msgb + ((long)side*512 + qs*64)*256 + head*64 + wv_*16 + lr;
#pragma unroll
  for (int a = 0; a < 4; ++a)
#pragma unroll
    for (int q_ = 0; q_ < 4; ++q_)
      o[(long)(a*16 + lk*4 + q_)*256] = f2b(mv[a][q_]);
}

// ffn: grid 8*nsides, 512 threads: z -> side=side0+z/8, slice=z&7
__global__ __launch_bounds__(512) void coarse_ffn(
    const u16* __restrict__ msgb, u16* __restrict__ cf, float* __restrict__ cff,
    const u16* __restrict__ Wm, const float* __restrict__ bm,
    const u16* __restrict__ W1, const float* __restrict__ b1,
    const u16* __restrict__ W2, const float* __restrict__ b2, int side0)
{
  __shared__ u16 m2[64*256];
  __shared__ u16 h1[64*512];
  int z = blockIdx.x;
  int side = side0 + (z >> 3), slice = z & 7;
  int wv_ = threadIdx.x >> 6, L = threadIdx.x & 63, lr = L & 15, lk = L >> 4;
  const u16* msg = msgb + ((long)side*512 + slice*64)*256;
  u16* x = cf + ((long)side*512 + slice*64)*256;
  float* xf = cff + ((long)side*512 + slice*64)*256;
  // wm
  for (int oi = 0; oi < 2; ++oi){
    int o0 = (wv_*2 + oi) << 4;
    f32x4 acc[4] = {};
    const u16* wrow = Wm + (long)(o0+lr)*256 + 8*lk;
#pragma unroll
    for (int ks = 0; ks < 8; ++ks){
      bf16x8 b = *(const bf16x8*)(wrow + ks*32);
#pragma unroll
      for (int a = 0; a < 4; ++a){
        bf16x8 av = *(const bf16x8*)(msg + (long)(a*16+lr)*256 + ks*32 + 8*lk);
        acc[a] = mfma16(av, b, acc[a]);
      }
    }
    int col = o0 + lr; float bb = bm[col];
#pragma unroll
    for (int a = 0; a < 4; ++a)
#pragma unroll
      for (int q_ = 0; q_ < 4; ++q_)
        m2[(a*16+lk*4+q_)*256 + col] = f2b(acc[a][q_] + bb);
  }
  __syncthreads();
  // w1 (concat [x | m2], relu)
  for (int oi = 0; oi < 4; ++oi){
    int o0 = (wv_*4 + oi) << 4;
    f32x4 acc[4] = {};
    const u16* wrow = W1 + (long)(o0+lr)*512 + 8*lk;
#pragma unroll
    for (int ks = 0; ks < 16; ++ks){
      int kk = ks*32;
      bf16x8 b = *(const bf16x8*)(wrow + kk);
#pragma unroll
      for (int a = 0; a < 4; ++a){
        bf16x8 av;
        if (kk < 256) av = *(const bf16x8*)(x + (long)(a*16+lr)*256 + kk + 8*lk);
        else          av = *(const bf16x8*)(&m2[(a*16+lr)*256 + kk - 256 + 8*lk]);
        acc[a] = mfma16(av, b, acc[a]);
      }
    }
    int col = o0 + lr; float bb = b1[col];
#pragma unroll
    for (int a = 0; a < 4; ++a)
#pragma unroll
      for (int q_ = 0; q_ < 4; ++q_)
        h1[(a*16+lk*4+q_)*512 + col] = f2b(fmaxf(acc[a][q_] + bb, 0.f));
  }
  __syncthreads();
  // w2 + residual (fp32 stream)
  for (int oi = 0; oi < 2; ++oi){
    int o0 = (wv_*2 + oi) << 4;
    f32x4 acc[4] = {};
    const u16* wrow = W2 + (long)(o0+lr)*512 + 8*lk;
#pragma unroll
    for (int ks = 0; ks < 16; ++ks){
      bf16x8 b = *(const bf16x8*)(wrow + ks*32);
#pragma unroll
      for (int a = 0; a < 4; ++a){
        bf16x8 av = *(const bf16x8*)(&h1[(a*16+lr)*512 + ks*32 + 8*lk]);
        acc[a] = mfma16(av, b, acc[a]);
      }
    }
    int col = o0 + lr; float bb = b2[col];
#pragma unroll
    for (int a = 0; a < 4; ++a)
#pragma unroll
      for (int q_ = 0; q_ < 4; ++q_){
        long idx = (long)(a*16+lk*4+q_)*256 + col;
        float v = acc[a][q_] + bb + xf[idx];
        xf[idx] = v;
        x[idx] = f2b(v);
      }
  }
}

// fp projection: grid 16: z -> side=z>>3, slice=z&7
__global__ __launch_bounds__(256) void coarse_proj(
    const u16* __restrict__ cf, const u16* __restrict__ W,
    const float* __restrict__ bias, u16* __restrict__ out)
{
  int z = blockIdx.x;
  int side = z >> 3, slice = z & 7;
  const u16* in = cf + (long)side*131072;
  u16* o = out + (long)side*131072;
  int n0 = slice << 6;
  int wv_ = threadIdx.x >> 6, L = threadIdx.x & 63, lr = L & 15, lk = L >> 4;
  const u16* inb = in + (long)(n0 + lr)*256 + 8*lk;
  for (int oi = 0; oi < 4; ++oi){
    int o0 = (wv_*4 + oi) << 4;
    const u16* wrow = W + (long)(o0 + lr)*256 + 8*lk;
    f32x4 acc[4] = {};
#pragma unroll
    for (int ks = 0; ks < 8; ++ks){
      bf16x8 b = *(const bf16x8*)(wrow + ks*32);
#pragma unroll
      for (int a = 0; a < 4; ++a){
        bf16x8 av = *(const bf16x8*)(inb + a*16*256 + ks*32);
        acc[a] = mfma16(av, b, acc[a]);
      }
    }
    int col = o0 + lr; float bb = bias[col];
#pragma unroll
    for (int a = 0; a < 4; ++a)
#pragma unroll
      for (int q_ = 0; q_ < 4; ++q_)
        o[(long)(n0 + a*16 + lk*4 + q_)*256 + col] = f2b(acc[a][q_] + bb);
  }
}

// Z[n][m] = sfp[n].tfp[m] / 16, grid (8,8)
__global__ __launch_bounds__(256) void coarse_scores(
    const u16* __restrict__ sfp, const u16* __restrict__ tfp, float* __restrict__ Z)
{
  int n0 = blockIdx.y << 6, m0 = blockIdx.x << 6;
  int wv_ = threadIdx.x >> 6, L = threadIdx.x & 63, lr = L & 15, lk = L >> 4;
  f32x4 acc[4] = {};
  const u16* arow = sfp + (long)(n0 + lr)*256 + 8*lk;
  const u16* brow = tfp + (long)(m0 + wv_*16 + lr)*256 + 8*lk;
#pragma unroll
  for (int ks = 0; ks < 8; ++ks){
    bf16x8 b = *(const bf16x8*)(brow + ks*32);
#pragma unroll
    for (int a = 0; a < 4; ++a){
      bf16x8 av = *(const bf16x8*)(arow + a*16*256 + ks*32);
      acc[a] = mfma16(av, b, acc[a]);
    }
  }
  int col = m0 + wv_*16 + lr;
#pragma unroll
  for (int a = 0; a < 4; ++a)
#pragma unroll
    for (int q_ = 0; q_ < 4; ++q_)
      Z[(long)(n0 + a*16 + lk*4 + q_)*513 + col] = acc[a][q_]*0.0625f;
}

// ======================= transport (exp-domain) =======================
__global__ __launch_bounds__(256) void fill_border(float* Z, const float* __restrict__ alpha)
{
  int i = blockIdx.x*256 + threadIdx.x;
  if (i < ZDIM){
    float a = alpha[0];
    Z[(long)i*ZDIM + (ZDIM-1)] = a;
    Z[(long)(ZDIM-1)*ZDIM + i] = a;
  }
}

__global__ __launch_bounds__(256) void transpose_k(const float* __restrict__ A,
                                                   float* __restrict__ B, int n)
{
  __shared__ float t[32][33];
  int bx = blockIdx.x*32, by = blockIdx.y*32;
  int lx = threadIdx.x & 31, ly0 = threadIdx.x >> 5;
  for (int dy = 0; dy < 32; dy += 8){
    int x = bx + lx, y = by + ly0 + dy;
    if (x < n && y < n) t[ly0+dy][lx] = A[(long)y*n + x];
  }
  __syncthreads();
  for (int dy = 0; dy < 32; dy += 8){
    int x = by + lx, y = bx + ly0 + dy;
    if (x < n && y < n) B[(long)y*n + x] = t[lx][ly0+dy];
  }
}

__global__ __launch_bounds__(64) void rowmax_k(const float* __restrict__ Z,
                                               const float* __restrict__ sub,
                                               float* __restrict__ out)
{
  int r = blockIdx.x;
  int lane = threadIdx.x;
  float m = -INFINITY;
  for (int j = lane; j < ZDIM; j += 64){
    float v = Z[(long)r*ZDIM + j];
    if (sub) v -= sub[j];
    m = fmaxf(m, v);
  }
  for (int o = 32; o; o >>= 1) m = fmaxf(m, __shfl_xor(m, o));
  if (lane == 0) out[r] = m;
}

__global__ __launch_bounds__(256) void expz_k(const float* __restrict__ Z,
                                              const float* __restrict__ Zt,
                                              const float* __restrict__ R,
                                              const float* __restrict__ C,
                                              float* __restrict__ eZ,
                                              float* __restrict__ eZT,
                                              float* __restrict__ wv)
{
  int i = blockIdx.x*256 + threadIdx.x;
  if (i < ZDIM) wv[i] = 1.f;
  if (i < ZDIM*ZDIM){
    int r = i / ZDIM, cc = i % ZDIM;
    eZ[i]  = expf(Z[i]  - R[r] - C[cc]);
    eZT[i] = expf(Zt[i] - C[r] - R[cc]);
  }
}

__global__ __launch_bounds__(256) void tmatvec(const float* __restrict__ E,
                                               const float* __restrict__ win,
                                               float* __restrict__ wout,
                                               float ebm, float ebl)
{
  __shared__ float w4[4];
  int r = blockIdx.x;
  int tid = threadIdx.x;
  const float* e = E + (long)r * ZDIM;
  float dot = 0.f;
  for (int j = tid; j < ZDIM; j += 256) dot = fmaf(e[j], win[j], dot);
  for (int o = 32; o; o >>= 1) dot += __shfl_xor(dot, o);
  if ((tid & 63) == 0) w4[tid >> 6] = dot;
  __syncthreads();
  if (tid == 0){
    float s = w4[0] + w4[1] + w4[2] + w4[3];
    wout[r] = ((r < ZDIM-1) ? ebm : ebl) / s;
  }
}

__global__ __launch_bounds__(256) void uvfinal_k(const float* __restrict__ wu,
                                                 const float* __restrict__ wvv,
                                                 const float* __restrict__ R,
                                                 const float* __restrict__ C,
                                                 float* __restrict__ u,
                                                 float* __restrict__ v)
{
  int i = blockIdx.x*256 + threadIdx.x;
  if (i < ZDIM){
    u[i] = logf(wu[i]) - R[i];
    v[i] = logf(wvv[i]) - C[i];
  }
}

__global__ __launch_bounds__(256) void transport_out(const float* __restrict__ Z,
                                                     const float* __restrict__ u,
                                                     const float* __restrict__ v,
                                                     float norm, float* __restrict__ out)
{
  int idx = blockIdx.x*256 + threadIdx.x;
  if (idx >= ZDIM*ZDIM) return;
  int r = idx / ZDIM, c = idx % ZDIM;
  out[idx] = Z[idx] + u[r] + v[c] - norm;
}

// ======================= local gather (bf16 [c][n][d]) =======================
__global__ __launch_bounds__(256) void gather_feats(const float* __restrict__ F,
                                                    const int* __restrict__ patch,
                                                    const int* __restrict__ corr,
                                                    int side, u16* __restrict__ out)
{
  int c = blockIdx.x;
  __shared__ int sel[KP];
  int tid = threadIdx.x;
  if (tid < KP){
    int node = corr[c*2 + side];
    sel[tid] = patch[node*KP + tid];
  }
  __syncthreads();
  for (int e = tid; e < KP*128; e += 256){
    int n = e >> 7, d = e & 127;
    out[((long)c*KP + n)*128 + d] = f2b(F[(long)sel[n]*128 + d]);
  }
}

// ======================= fused local transformer layer =======================
// grid nsides*256, 256 threads: z -> side=side0+(z>>8), c=z&255. In-place on X.
__global__ __launch_bounds__(256) void local_layer(
    u16* __restrict__ X, int cross, int side0,
    const u16* __restrict__ Wq, const u16* __restrict__ Wk,
    const u16* __restrict__ Wv, const u16* __restrict__ Wm,
    const u16* __restrict__ W1, const u16* __restrict__ W2,
    const float* __restrict__ bq, const float* __restrict__ bk,
    const float* __restrict__ bv, const float* __restrict__ bm,
    const float* __restrict__ b1, const float* __restrict__ b2)
{
  __shared__ u16 pool[32768];   // 64KB
  int z = blockIdx.x;
  int side = side0 + (z >> 8), c = z & 255;
  u16* x = X + ((long)side*256 + c)*8192;
  const u16* s = X + ((long)(cross ? 1-side : side)*256 + c)*8192;
  int wv_ = threadIdx.x >> 6, L = threadIdx.x & 63, lr = L & 15, lk = L >> 4;
  u16* qS = pool; u16* kS = pool + 8192; u16* vT = pool + 16384; u16* msgS = pool + 24576;

  // qkv (o-tiles wv_, wv_+4 per proj)
#pragma unroll
  for (int proj = 0; proj < 3; ++proj){
    const u16* in = proj ? s : x;
    const u16* W = proj==0?Wq:proj==1?Wk:Wv;
    const float* bi = proj==0?bq:proj==1?bk:bv;
#pragma unroll
    for (int oi = 0; oi < 2; ++oi){
      int o0 = (wv_ + oi*4) << 4;
      f32x4 acc[4] = {};
      const u16* wrow = W + (long)(o0+lr)*128 + 8*lk;
      const u16* inr = in + (long)lr*128 + 8*lk;
#pragma unroll
      for (int ks = 0; ks < 4; ++ks){
        bf16x8 b = *(const bf16x8*)(wrow + ks*32);
#pragma unroll
        for (int a = 0; a < 4; ++a){
          bf16x8 av = *(const bf16x8*)(inr + a*16*128 + ks*32);
          acc[a] = mfma16(av, b, acc[a]);
        }
      }
      int col = o0 + lr; float bb = bi[col];
      if (proj < 2){
        u16* dst = (proj==0 ? qS : kS);
#pragma unroll
        for (int a = 0; a < 4; ++a)
#pragma unroll
          for (int q_ = 0; q_ < 4; ++q_)
            dst[(a*16 + lk*4 + q_)*128 + col] = f2b(acc[a][q_] + bb);
      } else {
#pragma unroll
        for (int a = 0; a < 4; ++a)
#pragma unroll
          for (int q_ = 0; q_ < 4; ++q_)
            vT[col*64 + a*16 + lk*4 + q_] = f2b(acc[a][q_] + bb);
      }
    }
  }
  __syncthreads();
  // scores (wave = head), head dim 32
  int h = wv_;
  bf16x8 qf[4], kf[4];
#pragma unroll
  for (int a = 0; a < 4; ++a){
    qf[a] = *(const bf16x8*)(&qS[(a*16+lr)*128 + h*32 + 8*lk]);
    kf[a] = *(const bf16x8*)(&kS[(a*16+lr)*128 + h*32 + 8*lk]);
  }
  f32x4 sc[4][4] = {};
#pragma unroll
  for (int b = 0; b < 4; ++b)
#pragma unroll
    for (int a = 0; a < 4; ++a)
      sc[a][b] = mfma16(qf[a], kf[b], sc[a][b]);
  const float SCs = 0.17677669529663687f; // 1/sqrt(32)
  float invs[4][4];
#pragma unroll
  for (int a = 0; a < 4; ++a)
#pragma unroll
    for (int q_ = 0; q_ < 4; ++q_){
      float m = sc[a][0][q_];
#pragma unroll
      for (int b = 1; b < 4; ++b) m = fmaxf(m, sc[a][b][q_]);
      m = fmaxf(m, __shfl_xor(m, 1)); m = fmaxf(m, __shfl_xor(m, 2));
      m = fmaxf(m, __shfl_xor(m, 4)); m = fmaxf(m, __shfl_xor(m, 8));
      float ss = 0.f;
#pragma unroll
      for (int b = 0; b < 4; ++b){
        float e = __expf((sc[a][b][q_] - m)*SCs);
        sc[a][b][q_] = e; ss += e;
      }
      ss += __shfl_xor(ss,1); ss += __shfl_xor(ss,2); ss += __shfl_xor(ss,4); ss += __shfl_xor(ss,8);
      invs[a][q_] = 1.f/ss;
    }
  __syncthreads();   // all qS/kS reads done before P overwrites them
  u16* P = pool + h*4096;
#pragma unroll
  for (int a = 0; a < 4; ++a)
#pragma unroll
    for (int q_ = 0; q_ < 4; ++q_)
#pragma unroll
      for (int b = 0; b < 4; ++b)
        P[(a*16 + lk*4 + q_)*64 + b*16 + lr] = f2b(sc[a][b][q_] * invs[a][q_]);
  // PV (wave-local P, vT synced earlier)
  f32x4 mv[4][2] = {};
#pragma unroll
  for (int ks = 0; ks < 2; ++ks)
#pragma unroll
    for (int bt = 0; bt < 2; ++bt){
      bf16x8 bf = *(const bf16x8*)(&vT[(h*32 + bt*16 + lr)*64 + ks*32 + 8*lk]);
#pragma unroll
      for (int a = 0; a < 4; ++a){
        bf16x8 av = *(const bf16x8*)(&P[(a*16+lr)*64 + ks*32 + 8*lk]);
        mv[a][bt] = mfma16(av, bf, mv[a][bt]);
      }
    }
#pragma unroll
  for (int a = 0; a < 4; ++a)
#pragma unroll
    for (int bt = 0; bt < 2; ++bt)
#pragma unroll
      for (int q_ = 0; q_ < 4; ++q_)
        msgS[(a*16 + lk*4 + q_)*128 + h*32 + bt*16 + lr] = f2b(mv[a][bt][q_]);
  __syncthreads();
  // wm -> m2 (overlays P0/P1 area)
  u16* m2 = pool;
#pragma unroll
  for (int oi = 0; oi < 2; ++oi){
    int o0 = (wv_ + oi*4) << 4;
    f32x4 acc[4] = {};
    const u16* wrow = Wm + (long)(o0+lr)*128 + 8*lk;
#pragma unroll
    for (int ks = 0; ks < 4; ++ks){
      bf16x8 b = *(const bf16x8*)(wrow + ks*32);
#pragma unroll
      for (int a = 0; a < 4; ++a){
        bf16x8 av = *(const bf16x8*)(&msgS[(a*16+lr)*128 + ks*32 + 8*lk]);
        acc[a] = mfma16(av, b, acc[a]);
      }
    }
    int col = o0+lr; float bb = bm[col];
#pragma unroll
    for (int a = 0; a < 4; ++a)
#pragma unroll
      for (int q_ = 0; q_ < 4; ++q_)
        m2[(a*16+lk*4+q_)*128 + col] = f2b(acc[a][q_] + bb);
  }
  __syncthreads();
  // w1 -> h1 (overlays k/vT area), relu
  u16* h1 = pool + 8192;
#pragma unroll
  for (int oi = 0; oi < 4; ++oi){
    int o0 = (wv_*4 + oi) << 4;
    f32x4 acc[4] = {};
    const u16* wrow = W1 + (long)(o0+lr)*256 + 8*lk;
#pragma unroll
    for (int ks = 0; ks < 8; ++ks){
      int kk = ks*32;
      bf16x8 b = *(const bf16x8*)(wrow + kk);
#pragma unroll
      for (int a = 0; a < 4; ++a){
        bf16x8 av;
        if (kk < 128) av = *(const bf16x8*)(x + (long)(a*16+lr)*128 + kk + 8*lk);
        else          av = *(const bf16x8*)(&m2[(a*16+lr)*128 + kk - 128 + 8*lk]);
        acc[a] = mfma16(av, b, acc[a]);
      }
    }
    int col = o0+lr; float bb = b1[col];
#pragma unroll
    for (int a = 0; a < 4; ++a)
#pragma unroll
      for (int q_ = 0; q_ < 4; ++q_)
        h1[(a*16+lk*4+q_)*256 + col] = f2b(fmaxf(acc[a][q_] + bb, 0.f));
  }
  __syncthreads();
  // w2 + residual, in-place write
#pragma unroll
  for (int oi = 0; oi < 2; ++oi){
    int o0 = (wv_ + oi*4) << 4;
    f32x4 acc[4] = {};
    const u16* wrow = W2 + (long)(o0+lr)*256 + 8*lk;
#pragma unroll
    for (int ks = 0; ks < 8; ++ks){
      bf16x8 b = *(const bf16x8*)(wrow + ks*32);
#pragma unroll
      for (int a = 0; a < 4; ++a){
        bf16x8 av = *(const bf16x8*)(&h1[(a*16+lr)*256 + ks*32 + 8*lk]);
        acc[a] = mfma16(av, b, acc[a]);
      }
    }
    int col = o0+lr; float bb = b2[col];
#pragma unroll
    for (int a = 0; a < 4; ++a)
#pragma unroll
      for (int q_ = 0; q_ < 4; ++q_){
        int ri = (a*16+lk*4+q_)*128 + col;
        x[ri] = f2b(acc[a][q_] + bb + b2f(x[ri]));
      }
  }
}

// ======================= fused lfp + scores + exp-domain sinkhorn =======================
__global__ __launch_bounds__(1024) void sk_fused(
    const u16* __restrict__ X, const u16* __restrict__ lfpW, const float* __restrict__ lfpB,
    const int* __restrict__ corr, const int* __restrict__ cnt_s,
    const int* __restrict__ cnt_t, float* __restrict__ out)
{
  __shared__ u16 sp[8192], tp[8192];
  __shared__ float LA[65][66];
  __shared__ float E[65][66];
  __shared__ float Uacc[65], Vacc[65];
  int cpat = blockIdx.x;
  int tid = threadIdx.x;
  int wv_ = tid >> 6, L = tid & 63, lr = L & 15, lk = L >> 4;

  // lfp projection: waves 0-7 side A, 8-15 side B; o-tile = wv_&7
  {
    const u16* in = X + ((long)((wv_>>3)*256 + cpat))*8192;
    u16* dst = (wv_ < 8) ? sp : tp;
    int o0 = (wv_ & 7) << 4;
    f32x4 acc[4] = {};
    const u16* wrow = lfpW + (long)(o0+lr)*128 + 8*lk;
    const u16* inr = in + (long)lr*128 + 8*lk;
#pragma unroll
    for (int ks = 0; ks < 4; ++ks){
      bf16x8 b = *(const bf16x8*)(wrow + ks*32);
#pragma unroll
      for (int a = 0; a < 4; ++a){
        bf16x8 av = *(const bf16x8*)(inr + a*16*128 + ks*32);
        acc[a] = mfma16(av, b, acc[a]);
      }
    }
    int col = o0 + lr; float bb = lfpB[col];
#pragma unroll
    for (int a = 0; a < 4; ++a)
#pragma unroll
      for (int q_ = 0; q_ < 4; ++q_)
        dst[(a*16 + lk*4 + q_)*128 + col] = f2b(acc[a][q_] + bb);
  }
  __syncthreads();
  // scores: wave = (mt, nt)
  int cs = cnt_s[corr[cpat*2]], ct = cnt_t[corr[cpat*2+1]];
  {
    int mt = wv_ >> 2, nt = wv_ & 3;
    f32x4 acc = {};
    const u16* arow = sp + (mt*16 + lr)*128 + 8*lk;
    const u16* brow = tp + (nt*16 + lr)*128 + 8*lk;
#pragma unroll
    for (int ks = 0; ks < 4; ++ks){
      bf16x8 a = *(const bf16x8*)(arow + ks*32);
      bf16x8 b = *(const bf16x8*)(brow + ks*32);
      acc = mfma16(a, b, acc);
    }
    const float SCS = 0.08838834764831845f; // 1/sqrt(128)
#pragma unroll
    for (int q_ = 0; q_ < 4; ++q_){
      int row = mt*16 + lk*4 + q_;
      int col = nt*16 + lr;
      float v = acc[q_] * SCS;
      if (row >= cs || col >= ct) v = -1000000.0f;
      LA[row][col] = v;
    }
  }
  if (tid < 65){ LA[64][tid] = 0.f; LA[tid][64] = 0.f; Uacc[tid] = 0.f; Vacc[tid] = 0.f; }
  __syncthreads();
  int g = tid >> 4, sub = tid & 15;   // 64 groups x 16 lanes
  // first row phase in log domain (rows 0..63); E = exp(LA - U0)
  {
    float mx = -INFINITY;
    for (int j = sub; j < 65; j += 16) mx = fmaxf(mx, LA[g][j]);
    mx = fmaxf(mx, __shfl_xor(mx, 1)); mx = fmaxf(mx, __shfl_xor(mx, 2));
    mx = fmaxf(mx, __shfl_xor(mx, 4)); mx = fmaxf(mx, __shfl_xor(mx, 8));
    float s = 0.f;
    for (int j = sub; j < 65; j += 16) s += __expf(LA[g][j] - mx);
    s += __shfl_xor(s,1); s += __shfl_xor(s,2); s += __shfl_xor(s,4); s += __shfl_xor(s,8);
    float u0 = mx + __logf(s);
    if (sub == 0) Uacc[g] = u0;
    for (int j = sub; j < 65; j += 16) E[g][j] = __expf(LA[g][j] - u0);
  }
  if (tid < 65) E[64][tid] = 1.f;   // exp(LA[64][*]) = exp(0)
  __syncthreads();
  // 50 x (col phase, row phase) — row done 50x total counting the log one
  for (int it = 0; it < 50; ++it){
    // col phase: col g over 65 rows
    {
      float s = 0.f;
      for (int r = sub; r < 65; r += 16) s += E[r][g];
      s += __shfl_xor(s,1); s += __shfl_xor(s,2); s += __shfl_xor(s,4); s += __shfl_xor(s,8);
      if (sub == 0) Vacc[g] += __logf(s);
      float is = 1.f / s;
      for (int r = sub; r < 65; r += 16) E[r][g] *= is;
    }
    __syncthreads();
    if (it == 49) break;
    // row phase: row g over 65 cols
    {
      float s = 0.f;
      for (int j = sub; j < 65; j += 16) s += E[g][j];
      s += __shfl_xor(s,1); s += __shfl_xor(s,2); s += __shfl_xor(s,4); s += __shfl_xor(s,8);
      if (sub == 0) Uacc[g] += __logf(s);
      float is = 1.f / s;
      for (int j = sub; j < 65; j += 16) E[g][j] *= is;
    }
    __syncthreads();
  }
  __syncthreads();
  for (int e = tid; e < 4225; e += 1024){
    int r = e / 65, c2 = e % 65;
    out[(long)cpat*4225 + e] = LA[r][c2] - Uacc[r] - Vacc[c2];
  }
}

// ======================= GT (decision-exact) =======================
__global__ __launch_bounds__(256) void gt_kernel(const float* __restrict__ sraw,
                                                 const float* __restrict__ traw,
                                                 const float* __restrict__ rot,
                                                 const float* __restrict__ trans,
                                                 const int* __restrict__ patch_s,
                                                 const int* __restrict__ patch_t,
                                                 const int* __restrict__ corr,
                                                 const int* __restrict__ cnt_s,
                                                 const int* __restrict__ cnt_t,
                                                 float* __restrict__ out)
{
#pragma clang fp contract(off)
  int c = blockIdx.x, tid = threadIdx.x;
  int sn = corr[c*2], tn = corr[c*2+1];
  int cs = cnt_s[sn], ct = cnt_t[tn];
  __shared__ float sx[64], sy[64], sz[64], spp[64];
  __shared__ float txa[64], tya[64], tza[64], tpp[64];
  __shared__ float g[64][65];
  __shared__ float rowsum[64], colsum[64];
  if (tid < 64){
    int idx = patch_s[sn*KP + tid];
    float p0 = sraw[(long)idx*3], p1 = sraw[(long)idx*3+1], p2 = sraw[(long)idx*3+2];
    float a0 = fmaf(rot[2], p2, fmaf(rot[1], p1, rot[0]*p0)) + trans[0];
    float a1 = fmaf(rot[5], p2, fmaf(rot[4], p1, rot[3]*p0)) + trans[1];
    float a2 = fmaf(rot[8], p2, fmaf(rot[7], p1, rot[6]*p0)) + trans[2];
    sx[tid]=a0; sy[tid]=a1; sz[tid]=a2;
    spp[tid] = a0*a0 + a1*a1 + a2*a2;
  } else if (tid < 128){
    int l = tid - 64;
    int idx = patch_t[tn*KP + l];
    float p0 = traw[(long)idx*3], p1 = traw[(long)idx*3+1], p2 = traw[(long)idx*3+2];
    txa[l]=p0; tya[l]=p1; tza[l]=p2;
    tpp[l] = p0*p0 + p1*p1 + p2*p2;
  }
  __syncthreads();
  for (int e = tid; e < 4096; e += 256){
    int n = e >> 6, m = e & 63;
    float dot = fmaf(sz[n], tza[m], fmaf(sy[n], tya[m], sx[n]*txa[m]));
    float d2 = (spp[n] + tpp[m]) - 2.0f*dot;
    d2 = fmaxf(d2, 0.f);
    g[n][m] = (sqrtf(d2) < 0.1f) ? 1.f : 0.f;
  }
  __syncthreads();
  if (tid < 64){
    float s = 0.f;
    for (int m = 0; m < 64; ++m) s += g[tid][m];
    rowsum[tid] = fmaxf(1.f - s, 0.f);
  } else if (tid < 128){
    int m = tid - 64;
    float s = 0.f;
    for (int n = 0; n < 64; ++n) s += g[n][m];
    colsum[m] = fmaxf(1.f - s, 0.f);
  }
  __syncthreads();
  float* o = out + (long)c*4225;
  for (int e = tid; e < 4225; e += 256){
    int r = e / 65, col = e % 65;
    float v;
    if (r < 64 && col < 64) v = g[r][col];
    else if (r < 64)        v = rowsum[r];
    else if (col < 64)      v = colsum[col];
    else                    v = 0.f;
    if (r < 64 && r >= cs)    v = 0.f;
    if (col < 64 && col >= ct) v = 0.f;
    o[e] = v;
  }
}

// ======================= host =======================
extern "C" void kernel_launch(void* const* d_in, const int* in_sizes, int n_in,
                              void* d_out, int out_size, void* d_ws, size_t ws_size,
                              hipStream_t stream)
{
  const float* src_pcd_c  = (const float*)d_in[0];
  const float* tgt_pcd_c  = (const float*)d_in[1];
  const float* src_node_c = (const float*)d_in[2];
  const float* tgt_node_c = (const float*)d_in[3];
  const float* src_feats  = (const float*)d_in[4];
  const float* tgt_feats  = (const float*)d_in[5];
  const float* src_final  = (const float*)d_in[6];
  const float* tgt_final  = (const float*)d_in[7];
  const float* rot        = (const float*)d_in[8];
  const float* trans      = (const float*)d_in[9];
  const float* src_raw    = (const float*)d_in[10];
  const float* tgt_raw    = (const float*)d_in[11];
  const int*   node_corr  = (const int*)d_in[12];
  const float* c_wq = (const float*)d_in[13]; const float* c_bq = (const float*)d_in[14];
  const float* c_wk = (const float*)d_in[15]; const float* c_bk = (const float*)d_in[16];
  const float* c_wv = (const float*)d_in[17]; const float* c_bv = (const float*)d_in[18];
  const float* c_wm = (const float*)d_in[19]; const float* c_bm = (const float*)d_in[20];
  const float* c_w1 = (const float*)d_in[21]; const float* c_b1 = (const float*)d_in[22];
  const float* c_w2 = (const float*)d_in[23]; const float* c_b2 = (const float*)d_in[24];
  const float* l_wq = (const float*)d_in[25]; const float* l_bq = (const float*)d_in[26];
  const float* l_wk = (const float*)d_in[27]; const float* l_bk = (const float*)d_in[28];
  const float* l_wv = (const float*)d_in[29]; const float* l_bv = (const float*)d_in[30];
  const float* l_wm = (const float*)d_in[31]; const float* l_bm = (const float*)d_in[32];
  const float* l_w1 = (const float*)d_in[33]; const float* l_b1 = (const float*)d_in[34];
  const float* l_w2 = (const float*)d_in[35]; const float* l_b2 = (const float*)d_in[36];
  const float* fp_w = (const float*)d_in[37]; const float* fp_b = (const float*)d_in[38];
  const float* lfp_w = (const float*)d_in[39]; const float* lfp_b = (const float*)d_in[40];
  const float* bin_score = (const float*)d_in[41];

  const int NS = in_sizes[0] / 3;
  const int NT = in_sizes[1] / 3;

  float* FB = (float*)d_ws;
  size_t off = 0;
  auto falloc = [&](size_t n){ float* p = FB + off; off += (n + 63) & ~size_t(63); return p; };
  float* Zx  = falloc(263169);
  float* Zt  = falloc(263169);
  float* eZ  = falloc(263169);
  float* eZT = falloc(263169);
  float* Rr  = falloc(640);
  float* Cc  = falloc(640);
  float* wu  = falloc(640);
  float* wvec= falloc(640);
  float* uu  = falloc(640);
  float* vv  = falloc(640);
  float* cff = falloc(262144);             // fp32 residual stream [2][512][256]
  u16* cf   = (u16*)falloc(131072);        // [2][512][256] bf16
  u16* qb   = (u16*)falloc(131072);
  u16* kb   = (u16*)falloc(131072);
  u16* vtb  = (u16*)falloc(131072);        // [2][256][512]
  u16* msgb = (u16*)falloc(131072);
  u16* sfpb = (u16*)falloc(131072);        // [2][512][256]
  u16* X0   = (u16*)falloc(2097152);       // [2][256][64][128] bf16
  u16* wsb  = (u16*)falloc(1269760);       // 2539520 bf16 weights

  int* IB = (int*)(FB + off);
  size_t ioff = 0;
  auto ialloc = [&](size_t n){ int* p = IB + ioff; ioff += (n + 63) & ~size_t(63); return p; };
  int* id_s = ialloc(NS);
  int* id_t = ialloc(NT);
  const int nbs = (NS + 255) / 256, nbt = (NT + 255) / 256;
  int* hist_s = ialloc((size_t)nbs * NODES);
  int* hist_t = ialloc((size_t)nbt * NODES);
  int* cnt_s = ialloc(NODES);
  int* cnt_t = ialloc(NODES);
  int* patch_s = ialloc(NODES*KP);
  int* patch_t = ialloc(NODES*KP);

  float* out0 = (float*)d_out;
  float* out_ls = out0 + ZDIM*ZDIM;
  float* out_gt = out_ls + (long)CC*65*65;

  // bf16 weight pointers
  u16* WcQ = wsb + 0;
  u16* WcK = wsb + 196608;
  u16* WcV = wsb + 393216;
  u16* WcM = wsb + 589824;
  u16* Wc1 = wsb + 786432;
  u16* Wc2 = wsb + 1572864;
  u16* Wfp = wsb + 1966080;
  u16* WlQ = wsb + 2031616;
  u16* WlK = wsb + 2080768;
  u16* WlV = wsb + 2129920;
  u16* WlM = wsb + 2179072;
  u16* Wl1 = wsb + 2228224;
  u16* Wl2 = wsb + 2424832;
  u16* Wlfp = wsb + 2523136;

  // ---- weights -> bf16 ----
  conv_weights<<<(2539520+255)/256, 256, 0, stream>>>(
      c_wq, c_wk, c_wv, c_wm, c_w1, c_w2, fp_w,
      l_wq, l_wk, l_wv, l_wm, l_w1, l_w2, lfp_w, wsb);

  // ---- NN + patches ----
  nn_kernel<<<nbs, 256, 0, stream>>>(src_pcd_c, NS, src_node_c, id_s);
  nn_kernel<<<nbt, 256, 0, stream>>>(tgt_pcd_c, NT, tgt_node_c, id_t);
  hist_kernel<<<nbs, 256, 0, stream>>>(id_s, NS, hist_s);
  hist_kernel<<<nbt, 256, 0, stream>>>(id_t, NT, hist_t);
  scan_kernel<<<1, 512, 0, stream>>>(hist_s, nbs, cnt_s);
  scan_kernel<<<1, 512, 0, stream>>>(hist_t, nbt, cnt_t);
  hipMemsetAsync(patch_s, 0, NODES*KP*sizeof(int), stream);
  hipMemsetAsync(patch_t, 0, NODES*KP*sizeof(int), stream);
  rank_kernel<<<nbs, 256, 0, stream>>>(id_s, NS, hist_s, patch_s);
  rank_kernel<<<nbt, 256, 0, stream>>>(id_t, NT, hist_t, patch_t);

  // ---- coarse transformer ----
  tr_in<<<1024, 256, 0, stream>>>(src_feats, tgt_feats, cf, cff);
  int crossL[3] = {0, 1, 0};
  for (int l = 0; l < 3; ++l){
    u16* wq = WcQ + (size_t)l*65536; u16* wk = WcK + (size_t)l*65536;
    u16* wv = WcV + (size_t)l*65536; u16* wm = WcM + (size_t)l*65536;
    u16* w1 = Wc1 + (size_t)l*262144; u16* w2 = Wc2 + (size_t)l*131072;
    const float* bq = c_bq + (size_t)l*256; const float* bk = c_bk + (size_t)l*256;
    const float* bv = c_bv + (size_t)l*256; const float* bm = c_bm + (size_t)l*256;
    const float* b1 = c_b1 + (size_t)l*512; const float* b2 = c_b2 + (size_t)l*256;
    if (!crossL[l]){
      coarse_qkv<<<48, 256, 0, stream>>>(cf, 0, 0, wq, wk, wv, bq, bk, bv, qb, kb, vtb);
      coarse_attn<<<64, 256, 0, stream>>>(qb, kb, vtb, msgb, 0);
      coarse_ffn<<<16, 512, 0, stream>>>(msgb, cf, cff, wm, bm, w1, b1, w2, b2, 0);
    } else {
      for (int sd = 0; sd < 2; ++sd){
        coarse_qkv<<<24, 256, 0, stream>>>(cf, 1, sd, wq, wk, wv, bq, bk, bv, qb, kb, vtb);
        coarse_attn<<<32, 256, 0, stream>>>(qb, kb, vtb, msgb, sd);
        coarse_ffn<<<8, 512, 0, stream>>>(msgb, cf, cff, wm, bm, w1, b1, w2, b2, sd);
      }
    }
  }
  coarse_proj<<<16, 256, 0, stream>>>(cf, Wfp, fp_b, sfpb);
  coarse_scores<<<dim3(8,8), 256, 0, stream>>>(sfpb, sfpb + 131072, Zx);
  fill_border<<<3, 256, 0, stream>>>(Zx, bin_score);

  // ---- transport ----
  transpose_k<<<dim3(17,17), 256, 0, stream>>>(Zx, Zt, ZDIM);
  rowmax_k<<<ZDIM, 64, 0, stream>>>(Zx, nullptr, Rr);
  rowmax_k<<<ZDIM, 64, 0, stream>>>(Zt, Rr, Cc);
  expz_k<<<(ZDIM*ZDIM + 255)/256, 256, 0, stream>>>(Zx, Zt, Rr, Cc, eZ, eZT, wvec);
  const float EBM = 1.0f/1024.0f, EBL = 0.5f;
  for (int it = 0; it < 50; ++it){
    tmatvec<<<ZDIM, 256, 0, stream>>>(eZ,  wvec, wu, EBM, EBL);
    tmatvec<<<ZDIM, 256, 0, stream>>>(eZT, wu, wvec, EBM, EBL);
  }
  uvfinal_k<<<(ZDIM+255)/256, 256, 0, stream>>>(wu, wvec, Rr, Cc, uu, vv);
  const float NORM = (float)(-log(1024.0));
  transport_out<<<(ZDIM*ZDIM + 255)/256, 256, 0, stream>>>(Zx, uu, vv, NORM, out0);

  // ---- local transformer (fused per layer, in-place) ----
  gather_feats<<<CC, 256, 0, stream>>>(src_final, patch_s, node_corr, 0, X0);
  gather_feats<<<CC, 256, 0, stream>>>(tgt_final, patch_t, node_corr, 1, X0 + 2097152);
  for (int l = 0; l < 3; ++l){
    u16* wq = WlQ + (size_t)l*16384; u16* wk = WlK + (size_t)l*16384;
    u16* wv = WlV + (size_t)l*16384; u16* wm = WlM + (size_t)l*16384;
    u16* w1 = Wl1 + (size_t)l*65536; u16* w2 = Wl2 + (size_t)l*32768;
    const float* bq = l_bq + (size_t)l*128; const float* bk = l_bk + (size_t)l*128;
    const float* bv = l_bv + (size_t)l*128; const float* bm = l_bm + (size_t)l*128;
    const float* b1 = l_b1 + (size_t)l*256; const float* b2 = l_b2 + (size_t)l*128;
    if (!crossL[l]){
      local_layer<<<512, 256, 0, stream>>>(X0, 0, 0, wq,wk,wv,wm,w1,w2, bq,bk,bv,bm,b1,b2);
    } else {
      local_layer<<<256, 256, 0, stream>>>(X0, 1, 0, wq,wk,wv,wm,w1,w2, bq,bk,bv,bm,b1,b2);
      local_layer<<<256, 256, 0, stream>>>(X0, 1, 1, wq,wk,wv,wm,w1,w2, bq,bk,bv,bm,b1,b2);
    }
  }
  sk_fused<<<CC, 1024, 0, stream>>>(X0, Wlfp, lfp_b, node_corr, cnt_s, cnt_t, out_ls);

  // ---- GT ----
  gt_kernel<<<CC, 256, 0, stream>>>(src_raw, tgt_raw, rot, trans,
                                    patch_s, patch_t, node_corr, cnt_s, cnt_t, out_gt);

  (void)n_in; (void)out_size; (void)ws_size;
}